// Round 2
// baseline (7123.959 us; speedup 1.0000x reference)
//
#include <hip/hip_runtime.h>

#define NROWS 32768
#define KENT  8192
#define DDIM  256
#define BM    64
#define NBLK  (NROWS / BM)     // 512
#define EPK   128              // entries per kt step
#define KT    (KENT / EPK)     // 64
#define ND_TOTAL 8388608       // 32*1024*256

// ws layout: [0..4KB) double loss_part[512]

// ---------------- kernel 1: argmin, bit-faithful f32 semantics ----------------
// Reference (np, f32): d[n,k] = fl(fl(fl(||z||^2) + fl(||e||^2)) - fl(2*dot)).
// Facts used:
//  * fl(A + B_k) == A exactly: B_k <= 256*(1/8192)^2 = 3.8e-6 < half-ulp(A>=128) = 7.6e-6.
//  * argmin_k fl(A - C_k) (ties -> lowest index) is invariant to WHICH f32 value A is
//    within a binade (A, A' differ by a multiple of the grid step).
//  * np.matmul -> sgemm accumulates k sequentially with one fma accumulator per element;
//    sequential fmaf over k=0..255 reproduces C_k bit-exactly.
__global__ __launch_bounds__(256) void vq_argmin_kernel(
    const float* __restrict__ z, const float* __restrict__ cb,
    float* __restrict__ idx_out) {
  __shared__ float4 zs[BM * 64];   // 64KB, swizzled: [row][dq ^ ((row>>2)&3)<<1]
  const int tid = threadIdx.x;
  const int tc = tid & 15;         // entry group: 8 entries
  const int tr = tid >> 4;         // row group: 4 rows
  const int rowbase = blockIdx.x * BM;
  const float4* zg4 = (const float4*)z;
  const float4* cb4 = (const float4*)cb;
  const int swz = (tr & 3) << 1;

  // ---- stage z tile (coalesced global; XOR-swizzled LDS to kill 4-way read conflicts)
#pragma unroll
  for (int i = 0; i < 16; ++i) {
    int idx = i * 256 + tid;                       // [0, 4096)
    int row = idx >> 6, dq = idx & 63;
    int col = dq ^ (((row >> 2) & 3) << 1);
    zs[row * 64 + col] = zg4[(size_t)rowbase * 64 + idx];
  }
  __syncthreads();

  // ---- row norms A (any summation order is argmin-equivalent; butterfly is
  // lane-consistent since f32 add is commutative)
  float A[4];
#pragma unroll
  for (int r = 0; r < 4; ++r) {
    int row = tr * 4 + r;
    float p = 0.f;
#pragma unroll
    for (int j = 0; j < 4; ++j) {
      int dq = tc + 16 * j;
      float4 v = zs[row * 64 + (dq ^ swz)];
      p = fmaf(v.x, v.x, p); p = fmaf(v.y, v.y, p);
      p = fmaf(v.z, v.z, p); p = fmaf(v.w, v.w, p);
    }
#pragma unroll
    for (int m = 1; m <= 8; m <<= 1) p += __shfl_xor(p, m, 64);
    A[r] = p;
  }

  // ---- main loop: d = fl(A - 2*dot), sequential-k fma dot
  float b1[4] = {INFINITY, INFINITY, INFINITY, INFINITY};
  int   i1[4] = {0x7fffffff, 0x7fffffff, 0x7fffffff, 0x7fffffff};

  for (int kt = 0; kt < KT; ++kt) {
    const int e0 = kt * EPK + tc * 8;
    const float4* eb = cb4 + (size_t)e0 * 64;
    float acc[4][8];
#pragma unroll
    for (int r = 0; r < 4; ++r)
#pragma unroll
      for (int c = 0; c < 8; ++c) acc[r][c] = 0.f;

#pragma unroll 2
    for (int dq = 0; dq < 64; ++dq) {
      float4 ev[8];
#pragma unroll
      for (int c = 0; c < 8; ++c) ev[c] = eb[c * 64 + dq];
      const int col = dq ^ swz;
      float4 zv[4];
#pragma unroll
      for (int r = 0; r < 4; ++r) zv[r] = zs[(tr * 4 + r) * 64 + col];
#pragma unroll
      for (int r = 0; r < 4; ++r) {
#pragma unroll
        for (int c = 0; c < 8; ++c) {
          // strict k-ascending order: x,y,z,w — must not be reassociated
          acc[r][c] = fmaf(zv[r].x, ev[c].x, acc[r][c]);
          acc[r][c] = fmaf(zv[r].y, ev[c].y, acc[r][c]);
          acc[r][c] = fmaf(zv[r].z, ev[c].z, acc[r][c]);
          acc[r][c] = fmaf(zv[r].w, ev[c].w, acc[r][c]);
        }
      }
    }
#pragma unroll
    for (int c = 0; c < 8; ++c) {
#pragma unroll
      for (int r = 0; r < 4; ++r) {
        // fl(A - 2*acc): 2*acc is exact, so fma contraction is rounding-identical
        float d = A[r] - 2.0f * acc[r][c];
        if (d < b1[r]) { b1[r] = d; i1[r] = e0 + c; }   // strict <: keep lowest index
      }
    }
  }

  // ---- cross-thread reduction with lowest-index tie-break (ties are COMMON)
  __syncthreads();
  float* rs = (float*)zs;                 // [64][16]
  int*   ri = (int*)(rs + 64 * 16);       // [64][16]
#pragma unroll
  for (int r = 0; r < 4; ++r) {
    rs[(tr * 4 + r) * 16 + tc] = b1[r];
    ri[(tr * 4 + r) * 16 + tc] = i1[r];
  }
  __syncthreads();
  if (tid < BM) {
    float B = INFINITY; int I = 0x7fffffff;
#pragma unroll
    for (int c = 0; c < 16; ++c) {
      float v = rs[tid * 16 + c];
      int  ix = ri[tid * 16 + c];
      if (v < B || (v == B && ix < I)) { B = v; I = ix; }
    }
    idx_out[rowbase + tid] = (float)I;
  }
}

// ---------------- kernel 2: gather z_q, write z_q_st, per-block loss partials ----------------
__global__ __launch_bounds__(256) void vq_gather_kernel(
    const float* __restrict__ z, const float* __restrict__ cb,
    const float* __restrict__ idx_out, float* __restrict__ zq_out,
    double* __restrict__ loss_part) {
  __shared__ double lred[4];
  const int tid = threadIdx.x;
  const int rl = tid >> 2;
  const int part = tid & 3;
  const int R = blockIdx.x * 64 + rl;
  const int bi = (int)idx_out[R];
  const float4* zr = (const float4*)z + (size_t)R * 64 + part * 16;
  const float4* er = (const float4*)cb + (size_t)bi * 64 + part * 16;
  float4* orow = (float4*)zq_out + (size_t)R * 64 + part * 16;
  double lsum = 0.0;
#pragma unroll
  for (int i = 0; i < 16; ++i) {
    float4 zv = zr[i], ev = er[i];
    // mimic reference rounding: z + (zq - z) elementwise in f32
    float dx = ev.x - zv.x, dy = ev.y - zv.y, dz = ev.z - zv.z, dw = ev.w - zv.w;
    float4 o;
    o.x = zv.x + dx; o.y = zv.y + dy; o.z = zv.z + dz; o.w = zv.w + dw;
    orow[i] = o;
    lsum += (double)dx * dx + (double)dy * dy + (double)dz * dz + (double)dw * dw;
  }
#pragma unroll
  for (int o = 32; o > 0; o >>= 1) lsum += __shfl_down(lsum, o, 64);
  if ((tid & 63) == 0) lred[tid >> 6] = lsum;
  __syncthreads();
  if (tid == 0) loss_part[blockIdx.x] = lred[0] + lred[1] + lred[2] + lred[3];
}

// ---------------- kernel 3: finalize loss (deterministic) ----------------
__global__ void vq_finalize_kernel(const double* __restrict__ loss_part,
                                   float* __restrict__ loss_out) {
  if (threadIdx.x == 0 && blockIdx.x == 0) {
    double s = 0.0;
    for (int b = 0; b < NBLK; ++b) s += loss_part[b];
    // codebook_loss + 0.25*commitment (identical values in f32 reference)
    *loss_out = (float)(s / (double)ND_TOTAL * 1.25);
  }
}

extern "C" void kernel_launch(void* const* d_in, const int* in_sizes, int n_in,
                              void* d_out, int out_size, void* d_ws, size_t ws_size,
                              hipStream_t stream) {
  const float* z  = (const float*)d_in[0];
  const float* cb = (const float*)d_in[1];
  float* out = (float*)d_out;
  float* zq_out   = out;                       // [32,1024,256] f32
  float* loss_out = out + ND_TOTAL;            // scalar
  float* idx_out  = out + ND_TOTAL + 1;        // [32,1024] indices as f32 values

  double* loss_part = (double*)d_ws;           // [512]

  vq_argmin_kernel<<<NBLK, 256, 0, stream>>>(z, cb, idx_out);
  vq_gather_kernel<<<NBLK, 256, 0, stream>>>(z, cb, idx_out, zq_out, loss_part);
  vq_finalize_kernel<<<1, 64, 0, stream>>>(loss_part, loss_out);
}

// Round 3
// 2028.169 us; speedup vs baseline: 3.5125x; 3.5125x over previous
//
#include <hip/hip_runtime.h>

typedef unsigned int u32;
typedef unsigned long long u64;

#define NROWS 32768
#define KENT  8192
#define DDIM  256
#define ND_TOTAL 8388608
#define CAP   1048576u

// ---- workspace layout (bytes) ----
#define WS_COUNTER   0
#define WS_ROWMIN    64
#define WS_A         131136
#define WS_MARGIN    262208
#define WS_KEYS      393280
#define WS_CANDS     655424
#define WS_ZH        9044032
#define WS_EH        25821248
#define WS_LOSS      30015552
#define WS_NEEDED    30019648ull

typedef __attribute__((ext_vector_type(8))) short s16x8;
typedef __attribute__((ext_vector_type(4))) float f32x4;

__device__ __forceinline__ unsigned short bf16_rne(float f) {
  u32 u = __float_as_uint(f);
  u32 r = (u + 0x7fffu + ((u >> 16) & 1u)) >> 16;
  return (unsigned short)r;
}

// ---------------- prep: z -> bf16, A, margin, init rowmin/keys ----------------
__global__ __launch_bounds__(256) void vq_prep_z(
    const float* __restrict__ z, unsigned short* __restrict__ zh,
    float* __restrict__ A, float* __restrict__ marg,
    u32* __restrict__ rowmin, u64* __restrict__ keys) {
  const int wid = threadIdx.x >> 6, lane = threadIdx.x & 63;
  const int row = blockIdx.x * 4 + wid;
  float4 v = ((const float4*)z)[(size_t)row * 64 + lane];
  ushort4 h;
  h.x = bf16_rne(v.x); h.y = bf16_rne(v.y); h.z = bf16_rne(v.z); h.w = bf16_rne(v.w);
  *(ushort4*)&zh[(size_t)row * 256 + lane * 4] = h;
  double s  = (double)v.x * v.x + (double)v.y * v.y + (double)v.z * v.z + (double)v.w * v.w;
  double s1 = fabs((double)v.x) + fabs((double)v.y) + fabs((double)v.z) + fabs((double)v.w);
#pragma unroll
  for (int m = 1; m <= 32; m <<= 1) { s += __shfl_xor(s, m, 64); s1 += __shfl_xor(s1, m, 64); }
  if (lane == 0) {
    float Af = (float)s;
    u32 bits = __float_as_uint(Af);
    float ulpA = __uint_as_float((bits & 0x7f800000u) - (23u << 23));  // A >= 128 always
    A[row] = Af;
    // margin >= 4*B_dot + 4*ulpA + slack; B_dot = 2^-7*1.01*(1/8192)*S1 = 9.63e-7*S1
    marg[row] = 4.0f * ulpA + 3.86e-6f * (float)s1 + 4e-6f;
    rowmin[row] = 0x7f800000u;   // +inf bits (d~ is always positive)
    keys[row] = ~0ull;
  }
}

// ---------------- prep: codebook -> bf16, zero counter ----------------
__global__ __launch_bounds__(256) void vq_prep_e(
    const float* __restrict__ cb, unsigned short* __restrict__ eh,
    u32* __restrict__ counter) {
  if (blockIdx.x == 0 && threadIdx.x == 0) *counter = 0u;
  const int wid = threadIdx.x >> 6, lane = threadIdx.x & 63;
  const int row = blockIdx.x * 4 + wid;
  float4 v = ((const float4*)cb)[(size_t)row * 64 + lane];
  ushort4 h;
  h.x = bf16_rne(v.x); h.y = bf16_rne(v.y); h.z = bf16_rne(v.z); h.w = bf16_rne(v.w);
  *(ushort4*)&eh[(size_t)row * 256 + lane * 4] = h;
}

// ---------------- bf16 MFMA GEMM: pass 1 = rowmin, pass 2 = emit candidates ----------------
// 128x128 tile, BK=32, 4 waves, 16x16x32 MFMA, padded LDS (stride 40 bf16 = 80B, 16B-aligned).
template<int PASS>
__global__ __launch_bounds__(256) void vq_gemm(
    const unsigned short* __restrict__ zh, const unsigned short* __restrict__ eh,
    const float* __restrict__ A, const float* __restrict__ marg,
    u32* __restrict__ rowmin, u64* __restrict__ cands, u32* __restrict__ counter) {
  __shared__ __align__(16) unsigned short As[128 * 40];
  __shared__ __align__(16) unsigned short Bs[128 * 40];
  __shared__ float sA[128];
  const int tid = threadIdx.x;
  const int rowbase = blockIdx.y * 128, colbase = blockIdx.x * 128;
  if (tid < 128) sA[tid] = A[rowbase + tid];
  const int wid = tid >> 6, lane = tid & 63;
  const int wrow = (wid >> 1) * 64, wcol = (wid & 1) * 64;
  const int l15 = lane & 15, l4 = lane >> 4;
  const int r = tid >> 2, q = tid & 3;
  const s16x8* zg = (const s16x8*)zh;   // 8-elem units: row*32 + chunk
  const s16x8* eg = (const s16x8*)eh;
  f32x4 acc[4][4];
#pragma unroll
  for (int i = 0; i < 4; ++i)
#pragma unroll
    for (int j = 0; j < 4; ++j) acc[i][j] = (f32x4){0.f, 0.f, 0.f, 0.f};

  for (int kt = 0; kt < 8; ++kt) {
    const int kc = kt * 4 + q;
    s16x8 a0 = zg[(size_t)(rowbase + r) * 32 + kc];
    s16x8 a1 = zg[(size_t)(rowbase + r + 64) * 32 + kc];
    s16x8 b0 = eg[(size_t)(colbase + r) * 32 + kc];
    s16x8 b1 = eg[(size_t)(colbase + r + 64) * 32 + kc];
    __syncthreads();
    *(s16x8*)&As[r * 40 + q * 8] = a0;
    *(s16x8*)&As[(r + 64) * 40 + q * 8] = a1;
    *(s16x8*)&Bs[r * 40 + q * 8] = b0;
    *(s16x8*)&Bs[(r + 64) * 40 + q * 8] = b1;
    __syncthreads();
    s16x8 af[4], bfr[4];
#pragma unroll
    for (int fi = 0; fi < 4; ++fi)
      af[fi] = *(const s16x8*)&As[(wrow + fi * 16 + l15) * 40 + l4 * 8];
#pragma unroll
    for (int fj = 0; fj < 4; ++fj)
      bfr[fj] = *(const s16x8*)&Bs[(wcol + fj * 16 + l15) * 40 + l4 * 8];
#pragma unroll
    for (int fi = 0; fi < 4; ++fi)
#pragma unroll
      for (int fj = 0; fj < 4; ++fj)
        acc[fi][fj] = __builtin_amdgcn_mfma_f32_16x16x32_bf16(af[fi], bfr[fj], acc[fi][fj], 0, 0, 0);
  }

  // epilogue: C/D layout col = lane&15, row = (lane>>4)*4 + reg
#pragma unroll
  for (int fi = 0; fi < 4; ++fi) {
#pragma unroll
    for (int rg = 0; rg < 4; ++rg) {
      const int mloc = wrow + fi * 16 + l4 * 4 + rg;
      const int m = rowbase + mloc;
      const float Am = sA[mloc];
      if (PASS == 1) {
        float v = INFINITY;
#pragma unroll
        for (int fj = 0; fj < 4; ++fj) v = fminf(v, fmaf(-2.f, acc[fi][fj][rg], Am));
#pragma unroll
        for (int msk = 1; msk <= 8; msk <<= 1) v = fminf(v, __shfl_xor(v, msk, 64));
        if (l15 == 0) atomicMin(&rowmin[m], __float_as_uint(v));
      } else {
        const float thr = __uint_as_float(rowmin[m]) + marg[m];
#pragma unroll
        for (int fj = 0; fj < 4; ++fj) {
          float d = fmaf(-2.f, acc[fi][fj][rg], Am);
          if (d <= thr) {
            const int n = colbase + wcol + fj * 16 + l15;
            u32 pos = atomicAdd(counter, 1u);
            if (pos < CAP) cands[pos] = ((u64)(u32)m << 32) | (u64)(u32)n;
          }
        }
      }
    }
  }
}

// ---------------- exact resolution: reference-bit-faithful d for candidates ----------------
__global__ __launch_bounds__(256) void vq_exact(
    const float* __restrict__ z, const float* __restrict__ cb,
    const float* __restrict__ A, const u64* __restrict__ cands,
    const u32* __restrict__ counter, u64* __restrict__ keys) {
  u32 cnt = *counter; if (cnt > CAP) cnt = CAP;
  u32 i = blockIdx.x * 256 + threadIdx.x;
  if (i >= cnt) return;
  u64 c = cands[i];
  const int m = (int)(c >> 32), n = (int)(u32)(c & 0xffffffffull);
  const float4* zr = (const float4*)(z + (size_t)m * 256);
  const float4* er = (const float4*)(cb + (size_t)n * 256);
  float acc = 0.f;
  for (int j = 0; j < 64; ++j) {    // strict k-ascending sequential fma (sgemm-faithful)
    float4 a = zr[j], b = er[j];
    acc = fmaf(a.x, b.x, acc); acc = fmaf(a.y, b.y, acc);
    acc = fmaf(a.z, b.z, acc); acc = fmaf(a.w, b.w, acc);
  }
  float d = fmaf(-2.f, acc, A[m]);  // = fl(A - 2*acc), single rounding
  u64 key = ((u64)__float_as_uint(d) << 32) | (u64)(u32)n;  // lexicographic (d, index)
  atomicMin(&keys[m], key);
}

// ---------------- gather z_q, write z_q_st + indices, loss partials ----------------
__global__ __launch_bounds__(256) void vq_gather_new(
    const float* __restrict__ z, const float* __restrict__ cb,
    const u64* __restrict__ keys, float* __restrict__ idx_out,
    float* __restrict__ zq_out, double* __restrict__ loss_part) {
  __shared__ double lred[4];
  const int tid = threadIdx.x;
  const int rl = tid >> 2, part = tid & 3;
  const int R = blockIdx.x * 64 + rl;
  const int bi = (int)(u32)(keys[R] & 0xffffffffull);
  if (part == 0) idx_out[R] = (float)bi;
  const float4* zr = (const float4*)z + (size_t)R * 64 + part * 16;
  const float4* er = (const float4*)cb + (size_t)bi * 64 + part * 16;
  float4* orow = (float4*)zq_out + (size_t)R * 64 + part * 16;
  double lsum = 0.0;
#pragma unroll
  for (int i = 0; i < 16; ++i) {
    float4 zv = zr[i], ev = er[i];
    float dx = ev.x - zv.x, dy = ev.y - zv.y, dz = ev.z - zv.z, dw = ev.w - zv.w;
    float4 o; o.x = zv.x + dx; o.y = zv.y + dy; o.z = zv.z + dz; o.w = zv.w + dw;
    orow[i] = o;
    lsum += (double)dx * dx + (double)dy * dy + (double)dz * dz + (double)dw * dw;
  }
#pragma unroll
  for (int o = 32; o > 0; o >>= 1) lsum += __shfl_down(lsum, o, 64);
  if ((tid & 63) == 0) lred[tid >> 6] = lsum;
  __syncthreads();
  if (tid == 0) loss_part[blockIdx.x] = lred[0] + lred[1] + lred[2] + lred[3];
}

__global__ void vq_finalize_kernel(const double* __restrict__ loss_part,
                                   float* __restrict__ loss_out) {
  if (threadIdx.x == 0 && blockIdx.x == 0) {
    double s = 0.0;
    for (int b = 0; b < 512; ++b) s += loss_part[b];
    *loss_out = (float)(s / (double)ND_TOTAL * 1.25);
  }
}

// ================= fallback (proven round-2 path, used if ws too small) =================
__global__ __launch_bounds__(256) void vq_argmin_fb(
    const float* __restrict__ z, const float* __restrict__ cb,
    float* __restrict__ idx_out) {
  __shared__ float4 zs[64 * 64];
  const int tid = threadIdx.x;
  const int tc = tid & 15, tr = tid >> 4;
  const int rowbase = blockIdx.x * 64;
  const float4* zg4 = (const float4*)z;
  const float4* cb4 = (const float4*)cb;
  const int swz = (tr & 3) << 1;
#pragma unroll
  for (int i = 0; i < 16; ++i) {
    int idx = i * 256 + tid;
    int row = idx >> 6, dq = idx & 63;
    int col = dq ^ (((row >> 2) & 3) << 1);
    zs[row * 64 + col] = zg4[(size_t)rowbase * 64 + idx];
  }
  __syncthreads();
  float A[4];
#pragma unroll
  for (int r = 0; r < 4; ++r) {
    int row = tr * 4 + r;
    float p = 0.f;
#pragma unroll
    for (int j = 0; j < 4; ++j) {
      int dq = tc + 16 * j;
      float4 v = zs[row * 64 + (dq ^ swz)];
      p = fmaf(v.x, v.x, p); p = fmaf(v.y, v.y, p);
      p = fmaf(v.z, v.z, p); p = fmaf(v.w, v.w, p);
    }
#pragma unroll
    for (int m = 1; m <= 8; m <<= 1) p += __shfl_xor(p, m, 64);
    A[r] = p;
  }
  float b1[4] = {INFINITY, INFINITY, INFINITY, INFINITY};
  int   i1[4] = {0x7fffffff, 0x7fffffff, 0x7fffffff, 0x7fffffff};
  for (int kt = 0; kt < 64; ++kt) {
    const int e0 = kt * 128 + tc * 8;
    const float4* eb = cb4 + (size_t)e0 * 64;
    float acc[4][8];
#pragma unroll
    for (int r = 0; r < 4; ++r)
#pragma unroll
      for (int c = 0; c < 8; ++c) acc[r][c] = 0.f;
#pragma unroll 2
    for (int dq = 0; dq < 64; ++dq) {
      float4 ev[8];
#pragma unroll
      for (int c = 0; c < 8; ++c) ev[c] = eb[c * 64 + dq];
      const int col = dq ^ swz;
      float4 zv[4];
#pragma unroll
      for (int r = 0; r < 4; ++r) zv[r] = zs[(tr * 4 + r) * 64 + col];
#pragma unroll
      for (int r = 0; r < 4; ++r)
#pragma unroll
        for (int c = 0; c < 8; ++c) {
          acc[r][c] = fmaf(zv[r].x, ev[c].x, acc[r][c]);
          acc[r][c] = fmaf(zv[r].y, ev[c].y, acc[r][c]);
          acc[r][c] = fmaf(zv[r].z, ev[c].z, acc[r][c]);
          acc[r][c] = fmaf(zv[r].w, ev[c].w, acc[r][c]);
        }
    }
#pragma unroll
    for (int c = 0; c < 8; ++c)
#pragma unroll
      for (int r = 0; r < 4; ++r) {
        float d = A[r] - 2.0f * acc[r][c];
        if (d < b1[r]) { b1[r] = d; i1[r] = e0 + c; }
      }
  }
  __syncthreads();
  float* rs = (float*)zs;
  int*   ri = (int*)(rs + 64 * 16);
#pragma unroll
  for (int r = 0; r < 4; ++r) {
    rs[(tr * 4 + r) * 16 + tc] = b1[r];
    ri[(tr * 4 + r) * 16 + tc] = i1[r];
  }
  __syncthreads();
  if (tid < 64) {
    float B = INFINITY; int I = 0x7fffffff;
#pragma unroll
    for (int c = 0; c < 16; ++c) {
      float v = rs[tid * 16 + c];
      int  ix = ri[tid * 16 + c];
      if (v < B || (v == B && ix < I)) { B = v; I = ix; }
    }
    idx_out[rowbase + tid] = (float)I;
  }
}

__global__ __launch_bounds__(256) void vq_gather_fb(
    const float* __restrict__ z, const float* __restrict__ cb,
    const float* __restrict__ idx_out, float* __restrict__ zq_out,
    double* __restrict__ loss_part) {
  __shared__ double lred[4];
  const int tid = threadIdx.x;
  const int rl = tid >> 2, part = tid & 3;
  const int R = blockIdx.x * 64 + rl;
  const int bi = (int)idx_out[R];
  const float4* zr = (const float4*)z + (size_t)R * 64 + part * 16;
  const float4* er = (const float4*)cb + (size_t)bi * 64 + part * 16;
  float4* orow = (float4*)zq_out + (size_t)R * 64 + part * 16;
  double lsum = 0.0;
#pragma unroll
  for (int i = 0; i < 16; ++i) {
    float4 zv = zr[i], ev = er[i];
    float dx = ev.x - zv.x, dy = ev.y - zv.y, dz = ev.z - zv.z, dw = ev.w - zv.w;
    float4 o; o.x = zv.x + dx; o.y = zv.y + dy; o.z = zv.z + dz; o.w = zv.w + dw;
    orow[i] = o;
    lsum += (double)dx * dx + (double)dy * dy + (double)dz * dz + (double)dw * dw;
  }
#pragma unroll
  for (int o = 32; o > 0; o >>= 1) lsum += __shfl_down(lsum, o, 64);
  if ((tid & 63) == 0) lred[tid >> 6] = lsum;
  __syncthreads();
  if (tid == 0) loss_part[blockIdx.x] = lred[0] + lred[1] + lred[2] + lred[3];
}

extern "C" void kernel_launch(void* const* d_in, const int* in_sizes, int n_in,
                              void* d_out, int out_size, void* d_ws, size_t ws_size,
                              hipStream_t stream) {
  const float* z  = (const float*)d_in[0];
  const float* cb = (const float*)d_in[1];
  float* out = (float*)d_out;
  float* zq_out   = out;
  float* loss_out = out + ND_TOTAL;
  float* idx_out  = out + ND_TOTAL + 1;

  if (ws_size >= WS_NEEDED) {
    char* ws = (char*)d_ws;
    u32* counter          = (u32*)(ws + WS_COUNTER);
    u32* rowmin           = (u32*)(ws + WS_ROWMIN);
    float* A              = (float*)(ws + WS_A);
    float* marg           = (float*)(ws + WS_MARGIN);
    u64* keys             = (u64*)(ws + WS_KEYS);
    u64* cands            = (u64*)(ws + WS_CANDS);
    unsigned short* zh    = (unsigned short*)(ws + WS_ZH);
    unsigned short* eh    = (unsigned short*)(ws + WS_EH);
    double* loss_part     = (double*)(ws + WS_LOSS);

    vq_prep_z<<<NROWS / 4, 256, 0, stream>>>(z, zh, A, marg, rowmin, keys);
    vq_prep_e<<<KENT / 4, 256, 0, stream>>>(cb, eh, counter);
    vq_gemm<1><<<dim3(KENT / 128, NROWS / 128), 256, 0, stream>>>(zh, eh, A, marg, rowmin, cands, counter);
    vq_gemm<2><<<dim3(KENT / 128, NROWS / 128), 256, 0, stream>>>(zh, eh, A, marg, rowmin, cands, counter);
    vq_exact<<<CAP / 256, 256, 0, stream>>>(z, cb, A, cands, counter, keys);
    vq_gather_new<<<NROWS / 64, 256, 0, stream>>>(z, cb, keys, idx_out, zq_out, loss_part);
    vq_finalize_kernel<<<1, 64, 0, stream>>>(loss_part, loss_out);
  } else {
    double* loss_part = (double*)d_ws;   // [512]
    vq_argmin_fb<<<NROWS / 64, 256, 0, stream>>>(z, cb, idx_out);
    vq_gather_fb<<<NROWS / 64, 256, 0, stream>>>(z, cb, idx_out, zq_out, loss_part);
    vq_finalize_kernel<<<1, 64, 0, stream>>>(loss_part, loss_out);
  }
}

// Round 4
// 1967.558 us; speedup vs baseline: 3.6207x; 1.0308x over previous
//
#include <hip/hip_runtime.h>

typedef unsigned int u32;
typedef unsigned long long u64;
typedef unsigned short ushort_t;

#define NROWS 32768
#define KENT  8192
#define DDIM  256
#define ND_TOTAL 8388608
#define CAP   1048576u

// ---- workspace layout (bytes) ----
#define WS_COUNTER   0
#define WS_ROWMIN    64
#define WS_A         131136
#define WS_MARGIN    262208
#define WS_KEYS      393280
#define WS_CANDS     655424
#define WS_ZH        9044032
#define WS_EH        25821248
#define WS_LOSS      30015552
#define WS_NEEDED    30019648ull

typedef __attribute__((ext_vector_type(8))) short s16x8;
typedef __attribute__((ext_vector_type(4))) float f32x4;

__device__ __forceinline__ unsigned short bf16_rne(float f) {
  u32 u = __float_as_uint(f);
  u32 r = (u + 0x7fffu + ((u >> 16) & 1u)) >> 16;
  return (unsigned short)r;
}

// async global->LDS, 16B per lane, dest = wave-uniform base + lane*16
__device__ __forceinline__ void gll16(const void* g, void* l) {
  __builtin_amdgcn_global_load_lds((const __attribute__((address_space(1))) void*)g,
                                   (__attribute__((address_space(3))) void*)l, 16, 0, 0);
}

// ---------------- prep: z -> bf16, A, margin, init rowmin/keys ----------------
__global__ __launch_bounds__(256) void vq_prep_z(
    const float* __restrict__ z, unsigned short* __restrict__ zh,
    float* __restrict__ A, float* __restrict__ marg,
    u32* __restrict__ rowmin, u64* __restrict__ keys) {
  const int wid = threadIdx.x >> 6, lane = threadIdx.x & 63;
  const int row = blockIdx.x * 4 + wid;
  float4 v = ((const float4*)z)[(size_t)row * 64 + lane];
  ushort4 h;
  h.x = bf16_rne(v.x); h.y = bf16_rne(v.y); h.z = bf16_rne(v.z); h.w = bf16_rne(v.w);
  *(ushort4*)&zh[(size_t)row * 256 + lane * 4] = h;
  double s  = (double)v.x * v.x + (double)v.y * v.y + (double)v.z * v.z + (double)v.w * v.w;
  double s1 = fabs((double)v.x) + fabs((double)v.y) + fabs((double)v.z) + fabs((double)v.w);
#pragma unroll
  for (int m = 1; m <= 32; m <<= 1) { s += __shfl_xor(s, m, 64); s1 += __shfl_xor(s1, m, 64); }
  if (lane == 0) {
    float Af = (float)s;
    u32 bits = __float_as_uint(Af);
    float ulpA = __uint_as_float((bits & 0x7f800000u) - (23u << 23));  // A >= 128 always
    A[row] = Af;
    // margin >= 4*B_dot + 4*ulpA + slack; B_dot = 2^-7*1.01*(1/8192)*S1
    marg[row] = 4.0f * ulpA + 3.86e-6f * (float)s1 + 4e-6f;
    rowmin[row] = 0x7f800000u;   // +inf bits
    keys[row] = ~0ull;
  }
}

// ---------------- prep: codebook -> bf16, zero counter ----------------
__global__ __launch_bounds__(256) void vq_prep_e(
    const float* __restrict__ cb, unsigned short* __restrict__ eh,
    u32* __restrict__ counter) {
  if (blockIdx.x == 0 && threadIdx.x == 0) *counter = 0u;
  const int wid = threadIdx.x >> 6, lane = threadIdx.x & 63;
  const int row = blockIdx.x * 4 + wid;
  float4 v = ((const float4*)cb)[(size_t)row * 64 + lane];
  ushort4 h;
  h.x = bf16_rne(v.x); h.y = bf16_rne(v.y); h.z = bf16_rne(v.z); h.w = bf16_rne(v.w);
  *(ushort4*)&eh[(size_t)row * 256 + lane * 4] = h;
}

// ---------------- bf16 MFMA GEMM, m97 structure ----------------
// 128x128 tile, BK=32, NT=8 K-steps, 4 waves, global_load_lds staging,
// linear [128][32] LDS, double-buffered 2-phase pipeline.
// PASS 1: per-row global min (atomicMin). PASS 2: emit candidates <= thr.
template<int PASS>
__global__ __launch_bounds__(256) void vq_gemm2(
    const unsigned short* __restrict__ zh, const unsigned short* __restrict__ eh,
    const float* __restrict__ A, const float* __restrict__ marg,
    u32* __restrict__ rowmin, u64* __restrict__ cands, u32* __restrict__ counter) {
  __shared__ __align__(16) ushort_t As[2 * 4096];   // 2 bufs x 128x32 bf16
  __shared__ __align__(16) ushort_t Bs[2 * 4096];
  __shared__ float sA[128];
  __shared__ float sThr[128];

  // XCD-aware swizzle: nwg=16384, 2048/XCD; supergroups of 8 row-tiles,
  // col-tile fastest within supergroup -> A panel + streamed B stay in XCD L2.
  const int lin = blockIdx.x;
  const int xcd = lin & 7, c = lin >> 3;       // c in [0,2048)
  const int sg = c >> 9, cc = c & 511;         // 4 supergroups of 512
  const int rt = (xcd << 5) + (sg << 3) + (cc & 7);   // 0..255
  const int ct = cc >> 3;                      // 0..63
  const int rowbase = rt * 128, colbase = ct * 128;

  const int tid = threadIdx.x, wid = tid >> 6, lane = tid & 63;
  const int l15 = lane & 15, l4 = lane >> 4;
  const int wrow = (wid >> 1) * 64, wcol = (wid & 1) * 64;

  if (tid < 128) sA[tid] = A[rowbase + tid];
  if (PASS == 2 && tid >= 128)
    sThr[tid - 128] = __uint_as_float(rowmin[rowbase + tid - 128]) + marg[rowbase + tid - 128];

  // staging geometry: slot s in [0,512) <-> (row=s>>2, kc=s&3); lane covers
  // s = call*256 + wid*64 + lane; LDS linear: slot s at byte s*16.
  const int s0 = wid * 64 + lane, s1 = s0 + 256;
  const ushort_t* gA0 = zh + (size_t)(rowbase + (s0 >> 2)) * 256 + (s0 & 3) * 8;
  const ushort_t* gA1 = zh + (size_t)(rowbase + (s1 >> 2)) * 256 + (s1 & 3) * 8;
  const ushort_t* gB0 = eh + (size_t)(colbase + (s0 >> 2)) * 256 + (s0 & 3) * 8;
  const ushort_t* gB1 = eh + (size_t)(colbase + (s1 >> 2)) * 256 + (s1 & 3) * 8;

#define STAGE(buf, kt) do {                                         \
    gll16(gA0 + (kt) * 32, &As[(buf) * 4096 + wid * 512]);          \
    gll16(gA1 + (kt) * 32, &As[(buf) * 4096 + 2048 + wid * 512]);   \
    gll16(gB0 + (kt) * 32, &Bs[(buf) * 4096 + wid * 512]);          \
    gll16(gB1 + (kt) * 32, &Bs[(buf) * 4096 + 2048 + wid * 512]);   \
  } while (0)

  f32x4 acc[4][4];
#pragma unroll
  for (int i = 0; i < 4; ++i)
#pragma unroll
    for (int j = 0; j < 4; ++j) acc[i][j] = (f32x4){0.f, 0.f, 0.f, 0.f};

#define COMPUTE(buf) do {                                                          \
    s16x8 af[4], bv[4];                                                            \
    _Pragma("unroll")                                                              \
    for (int fi = 0; fi < 4; ++fi)                                                 \
      af[fi] = *(const s16x8*)&As[(buf) * 4096 + (wrow + fi * 16 + l15) * 32 + l4 * 8]; \
    _Pragma("unroll")                                                              \
    for (int fj = 0; fj < 4; ++fj)                                                 \
      bv[fj] = *(const s16x8*)&Bs[(buf) * 4096 + (wcol + fj * 16 + l15) * 32 + l4 * 8]; \
    _Pragma("unroll")                                                              \
    for (int fi = 0; fi < 4; ++fi)                                                 \
      _Pragma("unroll")                                                            \
      for (int fj = 0; fj < 4; ++fj)                                               \
        acc[fi][fj] = __builtin_amdgcn_mfma_f32_16x16x32_bf16(af[fi], bv[fj], acc[fi][fj], 0, 0, 0); \
  } while (0)

  // 2-phase pipeline: STAGE(next) before COMPUTE(cur); __syncthreads drains vmcnt.
  STAGE(0, 0);
  __syncthreads();
  int cur = 0;
#pragma unroll
  for (int kt = 0; kt < 7; ++kt) {
    STAGE(cur ^ 1, kt + 1);
    COMPUTE(cur);
    __syncthreads();
    cur ^= 1;
  }
  COMPUTE(cur);

  // epilogue: C/D layout col = wcol + fj*16 + (lane&15), row = wrow + fi*16 + (lane>>4)*4 + rg
#pragma unroll
  for (int fi = 0; fi < 4; ++fi) {
#pragma unroll
    for (int rg = 0; rg < 4; ++rg) {
      const int mloc = wrow + fi * 16 + l4 * 4 + rg;
      const float Am = sA[mloc];
      if (PASS == 1) {
        float v = INFINITY;
#pragma unroll
        for (int fj = 0; fj < 4; ++fj) v = fminf(v, fmaf(-2.f, acc[fi][fj][rg], Am));
#pragma unroll
        for (int msk = 1; msk <= 8; msk <<= 1) v = fminf(v, __shfl_xor(v, msk, 64));
        if (l15 == 0) atomicMin(&rowmin[rowbase + mloc], __float_as_uint(v));
      } else {
        const float thr = sThr[mloc];
#pragma unroll
        for (int fj = 0; fj < 4; ++fj) {
          float d = fmaf(-2.f, acc[fi][fj][rg], Am);
          if (d <= thr) {
            const int n = colbase + wcol + fj * 16 + l15;
            u32 pos = atomicAdd(counter, 1u);
            if (pos < CAP) cands[pos] = ((u64)(u32)(rowbase + mloc) << 32) | (u64)(u32)n;
          }
        }
      }
    }
  }
#undef STAGE
#undef COMPUTE
}

// ---------------- exact resolution: reference-bit-faithful f32 d ----------------
__global__ __launch_bounds__(256) void vq_exact(
    const float* __restrict__ z, const float* __restrict__ cb,
    const float* __restrict__ A, const u64* __restrict__ cands,
    const u32* __restrict__ counter, u64* __restrict__ keys) {
  u32 cnt = *counter; if (cnt > CAP) cnt = CAP;
  for (u32 i = blockIdx.x * 256 + threadIdx.x; i < cnt; i += gridDim.x * 256) {
    u64 c = cands[i];
    const int m = (int)(c >> 32), n = (int)(u32)(c & 0xffffffffull);
    const float4* zr = (const float4*)(z + (size_t)m * 256);
    const float4* er = (const float4*)(cb + (size_t)n * 256);
    float acc = 0.f;
    for (int j = 0; j < 64; ++j) {   // strict k-ascending sequential fma (sgemm-faithful)
      float4 a = zr[j], b = er[j];
      acc = fmaf(a.x, b.x, acc); acc = fmaf(a.y, b.y, acc);
      acc = fmaf(a.z, b.z, acc); acc = fmaf(a.w, b.w, acc);
    }
    float d = fmaf(-2.f, acc, A[m]);  // = fl(A - 2*acc), single rounding
    u64 key = ((u64)__float_as_uint(d) << 32) | (u64)(u32)n;
    atomicMin(&keys[m], key);
  }
}

// ---------------- gather z_q, write z_q_st + indices, loss partials ----------------
__global__ __launch_bounds__(256) void vq_gather_new(
    const float* __restrict__ z, const float* __restrict__ cb,
    const u64* __restrict__ keys, float* __restrict__ idx_out,
    float* __restrict__ zq_out, double* __restrict__ loss_part) {
  __shared__ double lred[4];
  const int tid = threadIdx.x;
  const int rl = tid >> 2, part = tid & 3;
  const int R = blockIdx.x * 64 + rl;
  const int bi = (int)(u32)(keys[R] & 0xffffffffull);
  if (part == 0) idx_out[R] = (float)bi;
  const float4* zr = (const float4*)z + (size_t)R * 64 + part * 16;
  const float4* er = (const float4*)cb + (size_t)bi * 64 + part * 16;
  float4* orow = (float4*)zq_out + (size_t)R * 64 + part * 16;
  double lsum = 0.0;
#pragma unroll
  for (int i = 0; i < 16; ++i) {
    float4 zv = zr[i], ev = er[i];
    float dx = ev.x - zv.x, dy = ev.y - zv.y, dz = ev.z - zv.z, dw = ev.w - zv.w;
    float4 o; o.x = zv.x + dx; o.y = zv.y + dy; o.z = zv.z + dz; o.w = zv.w + dw;
    orow[i] = o;
    lsum += (double)dx * dx + (double)dy * dy + (double)dz * dz + (double)dw * dw;
  }
#pragma unroll
  for (int o = 32; o > 0; o >>= 1) lsum += __shfl_down(lsum, o, 64);
  if ((tid & 63) == 0) lred[tid >> 6] = lsum;
  __syncthreads();
  if (tid == 0) loss_part[blockIdx.x] = lred[0] + lred[1] + lred[2] + lred[3];
}

__global__ void vq_finalize_kernel(const double* __restrict__ loss_part,
                                   float* __restrict__ loss_out) {
  if (threadIdx.x == 0 && blockIdx.x == 0) {
    double s = 0.0;
    for (int b = 0; b < 512; ++b) s += loss_part[b];
    *loss_out = (float)(s / (double)ND_TOTAL * 1.25);
  }
}

// ================= fallback (proven round-2 path, used if ws too small) =================
__global__ __launch_bounds__(256) void vq_argmin_fb(
    const float* __restrict__ z, const float* __restrict__ cb,
    float* __restrict__ idx_out) {
  __shared__ float4 zs[64 * 64];
  const int tid = threadIdx.x;
  const int tc = tid & 15, tr = tid >> 4;
  const int rowbase = blockIdx.x * 64;
  const float4* zg4 = (const float4*)z;
  const float4* cb4 = (const float4*)cb;
  const int swz = (tr & 3) << 1;
#pragma unroll
  for (int i = 0; i < 16; ++i) {
    int idx = i * 256 + tid;
    int row = idx >> 6, dq = idx & 63;
    int col = dq ^ (((row >> 2) & 3) << 1);
    zs[row * 64 + col] = zg4[(size_t)rowbase * 64 + idx];
  }
  __syncthreads();
  float A[4];
#pragma unroll
  for (int r = 0; r < 4; ++r) {
    int row = tr * 4 + r;
    float p = 0.f;
#pragma unroll
    for (int j = 0; j < 4; ++j) {
      int dq = tc + 16 * j;
      float4 v = zs[row * 64 + (dq ^ swz)];
      p = fmaf(v.x, v.x, p); p = fmaf(v.y, v.y, p);
      p = fmaf(v.z, v.z, p); p = fmaf(v.w, v.w, p);
    }
#pragma unroll
    for (int m = 1; m <= 8; m <<= 1) p += __shfl_xor(p, m, 64);
    A[r] = p;
  }
  float b1[4] = {INFINITY, INFINITY, INFINITY, INFINITY};
  int   i1[4] = {0x7fffffff, 0x7fffffff, 0x7fffffff, 0x7fffffff};
  for (int kt = 0; kt < 64; ++kt) {
    const int e0 = kt * 128 + tc * 8;
    const float4* eb = cb4 + (size_t)e0 * 64;
    float acc[4][8];
#pragma unroll
    for (int r = 0; r < 4; ++r)
#pragma unroll
      for (int c = 0; c < 8; ++c) acc[r][c] = 0.f;
#pragma unroll 2
    for (int dq = 0; dq < 64; ++dq) {
      float4 ev[8];
#pragma unroll
      for (int c = 0; c < 8; ++c) ev[c] = eb[c * 64 + dq];
      const int col = dq ^ swz;
      float4 zv[4];
#pragma unroll
      for (int r = 0; r < 4; ++r) zv[r] = zs[(tr * 4 + r) * 64 + col];
#pragma unroll
      for (int r = 0; r < 4; ++r)
#pragma unroll
        for (int c = 0; c < 8; ++c) {
          acc[r][c] = fmaf(zv[r].x, ev[c].x, acc[r][c]);
          acc[r][c] = fmaf(zv[r].y, ev[c].y, acc[r][c]);
          acc[r][c] = fmaf(zv[r].z, ev[c].z, acc[r][c]);
          acc[r][c] = fmaf(zv[r].w, ev[c].w, acc[r][c]);
        }
    }
#pragma unroll
    for (int c = 0; c < 8; ++c)
#pragma unroll
      for (int r = 0; r < 4; ++r) {
        float d = A[r] - 2.0f * acc[r][c];
        if (d < b1[r]) { b1[r] = d; i1[r] = e0 + c; }
      }
  }
  __syncthreads();
  float* rs = (float*)zs;
  int*   ri = (int*)(rs + 64 * 16);
#pragma unroll
  for (int r = 0; r < 4; ++r) {
    rs[(tr * 4 + r) * 16 + tc] = b1[r];
    ri[(tr * 4 + r) * 16 + tc] = i1[r];
  }
  __syncthreads();
  if (tid < 64) {
    float B = INFINITY; int I = 0x7fffffff;
#pragma unroll
    for (int c = 0; c < 16; ++c) {
      float v = rs[tid * 16 + c];
      int  ix = ri[tid * 16 + c];
      if (v < B || (v == B && ix < I)) { B = v; I = ix; }
    }
    idx_out[rowbase + tid] = (float)I;
  }
}

__global__ __launch_bounds__(256) void vq_gather_fb(
    const float* __restrict__ z, const float* __restrict__ cb,
    const float* __restrict__ idx_out, float* __restrict__ zq_out,
    double* __restrict__ loss_part) {
  __shared__ double lred[4];
  const int tid = threadIdx.x;
  const int rl = tid >> 2, part = tid & 3;
  const int R = blockIdx.x * 64 + rl;
  const int bi = (int)idx_out[R];
  const float4* zr = (const float4*)z + (size_t)R * 64 + part * 16;
  const float4* er = (const float4*)cb + (size_t)bi * 64 + part * 16;
  float4* orow = (float4*)zq_out + (size_t)R * 64 + part * 16;
  double lsum = 0.0;
#pragma unroll
  for (int i = 0; i < 16; ++i) {
    float4 zv = zr[i], ev = er[i];
    float dx = ev.x - zv.x, dy = ev.y - zv.y, dz = ev.z - zv.z, dw = ev.w - zv.w;
    float4 o; o.x = zv.x + dx; o.y = zv.y + dy; o.z = zv.z + dz; o.w = zv.w + dw;
    orow[i] = o;
    lsum += (double)dx * dx + (double)dy * dy + (double)dz * dz + (double)dw * dw;
  }
#pragma unroll
  for (int o = 32; o > 0; o >>= 1) lsum += __shfl_down(lsum, o, 64);
  if ((tid & 63) == 0) lred[tid >> 6] = lsum;
  __syncthreads();
  if (tid == 0) loss_part[blockIdx.x] = lred[0] + lred[1] + lred[2] + lred[3];
}

extern "C" void kernel_launch(void* const* d_in, const int* in_sizes, int n_in,
                              void* d_out, int out_size, void* d_ws, size_t ws_size,
                              hipStream_t stream) {
  const float* z  = (const float*)d_in[0];
  const float* cb = (const float*)d_in[1];
  float* out = (float*)d_out;
  float* zq_out   = out;
  float* loss_out = out + ND_TOTAL;
  float* idx_out  = out + ND_TOTAL + 1;

  if (ws_size >= WS_NEEDED) {
    char* ws = (char*)d_ws;
    u32* counter          = (u32*)(ws + WS_COUNTER);
    u32* rowmin           = (u32*)(ws + WS_ROWMIN);
    float* A              = (float*)(ws + WS_A);
    float* marg           = (float*)(ws + WS_MARGIN);
    u64* keys             = (u64*)(ws + WS_KEYS);
    u64* cands            = (u64*)(ws + WS_CANDS);
    unsigned short* zh    = (unsigned short*)(ws + WS_ZH);
    unsigned short* eh    = (unsigned short*)(ws + WS_EH);
    double* loss_part     = (double*)(ws + WS_LOSS);

    vq_prep_z<<<NROWS / 4, 256, 0, stream>>>(z, zh, A, marg, rowmin, keys);
    vq_prep_e<<<KENT / 4, 256, 0, stream>>>(cb, eh, counter);
    vq_gemm2<1><<<16384, 256, 0, stream>>>(zh, eh, A, marg, rowmin, cands, counter);
    vq_gemm2<2><<<16384, 256, 0, stream>>>(zh, eh, A, marg, rowmin, cands, counter);
    vq_exact<<<2048, 256, 0, stream>>>(z, cb, A, cands, counter, keys);
    vq_gather_new<<<NROWS / 64, 256, 0, stream>>>(z, cb, keys, idx_out, zq_out, loss_part);
    vq_finalize_kernel<<<1, 64, 0, stream>>>(loss_part, loss_out);
  } else {
    double* loss_part = (double*)d_ws;   // [512]
    vq_argmin_fb<<<NROWS / 64, 256, 0, stream>>>(z, cb, idx_out);
    vq_gather_fb<<<NROWS / 64, 256, 0, stream>>>(z, cb, idx_out, zq_out, loss_part);
    vq_finalize_kernel<<<1, 64, 0, stream>>>(loss_part, loss_out);
  }
}

// Round 5
// 1917.406 us; speedup vs baseline: 3.7154x; 1.0262x over previous
//
#include <hip/hip_runtime.h>

typedef unsigned int u32;
typedef unsigned long long u64;
typedef unsigned short ushort_t;

#define NROWS 32768
#define KENT  8192
#define DDIM  256
#define ND_TOTAL 8388608
#define CAP   1048576u

// ---- workspace layout (bytes) ----
#define WS_COUNTER   0
#define WS_A         64
#define WS_MARG      131136
#define WS_KEYS      262208
#define WS_CANDS     524352
#define WS_ZH        8912960
#define WS_EH        25690176
#define WS_LOSS      29884480
#define WS_NEEDED    29888576ull

typedef __attribute__((ext_vector_type(8))) short s16x8;
typedef __attribute__((ext_vector_type(4))) float f32x4;

__device__ __forceinline__ unsigned short bf16_rne(float f) {
  u32 u = __float_as_uint(f);
  u32 r = (u + 0x7fffu + ((u >> 16) & 1u)) >> 16;
  return (unsigned short)r;
}

// async global->LDS: 16B/lane, LDS dest = wave-uniform base + lane*16
__device__ __forceinline__ void gll16(const void* g, void* l) {
  __builtin_amdgcn_global_load_lds((const __attribute__((address_space(1))) void*)g,
                                   (__attribute__((address_space(3))) void*)l, 16, 0, 0);
}

// ---------------- prep: z -> bf16, A, margin, init keys ----------------
__global__ __launch_bounds__(256) void vq_prep_z(
    const float* __restrict__ z, unsigned short* __restrict__ zh,
    float* __restrict__ A, float* __restrict__ marg, u64* __restrict__ keys) {
  const int wid = threadIdx.x >> 6, lane = threadIdx.x & 63;
  const int row = blockIdx.x * 4 + wid;
  float4 v = ((const float4*)z)[(size_t)row * 64 + lane];
  ushort4 h;
  h.x = bf16_rne(v.x); h.y = bf16_rne(v.y); h.z = bf16_rne(v.z); h.w = bf16_rne(v.w);
  *(ushort4*)&zh[(size_t)row * 256 + lane * 4] = h;
  double s  = (double)v.x * v.x + (double)v.y * v.y + (double)v.z * v.z + (double)v.w * v.w;
  double s1 = fabs((double)v.x) + fabs((double)v.y) + fabs((double)v.z) + fabs((double)v.w);
#pragma unroll
  for (int m = 1; m <= 32; m <<= 1) { s += __shfl_xor(s, m, 64); s1 += __shfl_xor(s1, m, 64); }
  if (lane == 0) {
    float Af = (float)s;
    u32 bits = __float_as_uint(Af);
    float ulpA = __uint_as_float((bits & 0x7f800000u) - (23u << 23));  // A >= 128 always
    A[row] = Af;
    // marg >= 2E, E = bf16-conversion + rounding bound (proven rounds 3/4)
    marg[row] = 4.0f * ulpA + 3.86e-6f * (float)s1 + 4e-6f;
    keys[row] = ~0ull;
  }
}

// ---------------- prep: codebook -> bf16, zero counter ----------------
__global__ __launch_bounds__(256) void vq_prep_e(
    const float* __restrict__ cb, unsigned short* __restrict__ eh,
    u32* __restrict__ counter) {
  if (blockIdx.x == 0 && threadIdx.x == 0) *counter = 0u;
  const int wid = threadIdx.x >> 6, lane = threadIdx.x & 63;
  const int row = blockIdx.x * 4 + wid;
  float4 v = ((const float4*)cb)[(size_t)row * 64 + lane];
  ushort4 h;
  h.x = bf16_rne(v.x); h.y = bf16_rne(v.y); h.z = bf16_rne(v.z); h.w = bf16_rne(v.w);
  *(ushort4*)&eh[(size_t)row * 256 + lane * 4] = h;
}

// ---------------- fused GEMM: 64-row panel/block, A-frags in registers,
// B streamed through dbuf LDS over 512 pipeline steps; sweep1 = rowmin,
// sweep2 = emit candidates (identical DAG -> bitwise-identical d~) ----------------
__global__ __launch_bounds__(256) void vq_fused(
    const ushort_t* __restrict__ zh, const ushort_t* __restrict__ eh,
    const float* __restrict__ A, const float* __restrict__ marg,
    u64* __restrict__ cands, u32* __restrict__ counter) {
  __shared__ __align__(16) ushort_t Bsm[2 * 4096];   // 2 x (128 entries x 32 dims) bf16
  __shared__ float rowMinSm[64][2];

  const int tid = threadIdx.x, wid = tid >> 6, lane = tid & 63;
  const int l15 = lane & 15, l4 = lane >> 4;
  const int wrow = (wid >> 1) * 32, wcol = (wid & 1) * 64;
  const int rowbase = blockIdx.x * 64;

  // ---- A fragments: registers for the whole kernel (row, dims kt*32+l4*8)
  s16x8 areg[2][8];
#pragma unroll
  for (int fi = 0; fi < 2; ++fi)
#pragma unroll
    for (int kt = 0; kt < 8; ++kt)
      areg[fi][kt] = *(const s16x8*)(zh + (size_t)(rowbase + wrow + fi * 16 + l15) * 256
                                        + kt * 32 + l4 * 8);

  // per-thread row constants (8 rows: fi in {0,1}, rg in {0..3})
  float Am[2][4], Mg[2][4];
#pragma unroll
  for (int fi = 0; fi < 2; ++fi)
#pragma unroll
    for (int rg = 0; rg < 4; ++rg) {
      int r = rowbase + wrow + fi * 16 + l4 * 4 + rg;
      Am[fi][rg] = A[r];
      Mg[fi][rg] = marg[r];
    }

  // ---- B staging geometry: LDS slot t (byte t*16) holds entry e=t>>2,
  // chunk kc = (t&3) ^ ((e>>1)&3)  (XOR swizzle; read with same involution -> 2-way free)
  const int t0 = wid * 64 + lane, t1 = t0 + 256;
  const int e0s = t0 >> 2, e1s = t1 >> 2;
  const ushort_t* gB0 = eh + (size_t)e0s * 256 + (((t0 & 3) ^ ((e0s >> 1) & 3)) * 8);
  const ushort_t* gB1 = eh + (size_t)e1s * 256 + (((t1 & 3) ^ ((e1s >> 1) & 3)) * 8);

#define STAGEB(buf, ct, kt) do {                                              \
    gll16(gB0 + (size_t)(ct) * 32768 + (kt) * 32, &Bsm[(buf) * 4096 + wid * 512]);        \
    gll16(gB1 + (size_t)(ct) * 32768 + (kt) * 32, &Bsm[(buf) * 4096 + 2048 + wid * 512]); \
  } while (0)

  int boff[4];
#pragma unroll
  for (int fj = 0; fj < 4; ++fj) {
    int e = wcol + fj * 16 + l15;
    boff[fj] = (e * 4 + (l4 ^ ((e >> 1) & 3))) * 8;
  }

  float run[2][4], thr[2][4];
#pragma unroll
  for (int fi = 0; fi < 2; ++fi)
#pragma unroll
    for (int rg = 0; rg < 4; ++rg) run[fi][rg] = INFINITY;

#pragma unroll
  for (int sweep = 0; sweep < 2; ++sweep) {
    STAGEB(0, 0, 0);
    __syncthreads();
#pragma unroll 1
    for (int ct = 0; ct < 64; ++ct) {
      f32x4 acc[2][4];
#pragma unroll
      for (int fi = 0; fi < 2; ++fi)
#pragma unroll
        for (int fj = 0; fj < 4; ++fj) acc[fi][fj] = (f32x4){0.f, 0.f, 0.f, 0.f};

#pragma unroll
      for (int kt = 0; kt < 8; ++kt) {
        if (kt < 7) { STAGEB((kt & 1) ^ 1, ct, kt + 1); }
        else if (ct < 63) { STAGEB((kt & 1) ^ 1, ct + 1, 0); }
        s16x8 bv[4];
#pragma unroll
        for (int fj = 0; fj < 4; ++fj)
          bv[fj] = *(const s16x8*)&Bsm[(kt & 1) * 4096 + boff[fj]];
#pragma unroll
        for (int fi = 0; fi < 2; ++fi)
#pragma unroll
          for (int fj = 0; fj < 4; ++fj)
            acc[fi][fj] = __builtin_amdgcn_mfma_f32_16x16x32_bf16(areg[fi][kt], bv[fj],
                                                                  acc[fi][fj], 0, 0, 0);
        __syncthreads();
      }

      // per-tile epilogue (registers only)
#pragma unroll
      for (int fi = 0; fi < 2; ++fi)
#pragma unroll
        for (int rg = 0; rg < 4; ++rg) {
          float d0 = fmaf(-2.f, acc[fi][0][rg], Am[fi][rg]);
          float d1 = fmaf(-2.f, acc[fi][1][rg], Am[fi][rg]);
          float d2 = fmaf(-2.f, acc[fi][2][rg], Am[fi][rg]);
          float d3 = fmaf(-2.f, acc[fi][3][rg], Am[fi][rg]);
          if (sweep == 0) {
            run[fi][rg] = fminf(run[fi][rg], fminf(fminf(d0, d1), fminf(d2, d3)));
          } else {
            const float T = thr[fi][rg];
            const int m = rowbase + wrow + fi * 16 + l4 * 4 + rg;
            const int nb = ct * 128 + wcol + l15;
            if (d0 <= T) { u32 p = atomicAdd(counter, 1u); if (p < CAP) cands[p] = ((u64)(u32)m << 32) | (u64)(u32)(nb); }
            if (d1 <= T) { u32 p = atomicAdd(counter, 1u); if (p < CAP) cands[p] = ((u64)(u32)m << 32) | (u64)(u32)(nb + 16); }
            if (d2 <= T) { u32 p = atomicAdd(counter, 1u); if (p < CAP) cands[p] = ((u64)(u32)m << 32) | (u64)(u32)(nb + 32); }
            if (d3 <= T) { u32 p = atomicAdd(counter, 1u); if (p < CAP) cands[p] = ((u64)(u32)m << 32) | (u64)(u32)(nb + 48); }
          }
        }
    }

    if (sweep == 0) {
      // cross-lane (16-lane group) reduce, publish per (row, col-half), combine
#pragma unroll
      for (int fi = 0; fi < 2; ++fi)
#pragma unroll
        for (int rg = 0; rg < 4; ++rg) {
          float v = run[fi][rg];
#pragma unroll
          for (int msk = 1; msk <= 8; msk <<= 1) v = fminf(v, __shfl_xor(v, msk, 64));
          if (l15 == 0) rowMinSm[wrow + fi * 16 + l4 * 4 + rg][wid & 1] = v;
        }
      __syncthreads();
#pragma unroll
      for (int fi = 0; fi < 2; ++fi)
#pragma unroll
        for (int rg = 0; rg < 4; ++rg) {
          int rl = wrow + fi * 16 + l4 * 4 + rg;
          thr[fi][rg] = fminf(rowMinSm[rl][0], rowMinSm[rl][1]) + Mg[fi][rg];
        }
      __syncthreads();
    }
  }
#undef STAGEB
}

// ---------------- exact resolution: reference-bit-faithful f32 d ----------------
__global__ __launch_bounds__(256) void vq_exact(
    const float* __restrict__ z, const float* __restrict__ cb,
    const float* __restrict__ A, const u64* __restrict__ cands,
    const u32* __restrict__ counter, u64* __restrict__ keys) {
  u32 cnt = *counter; if (cnt > CAP) cnt = CAP;
  for (u32 i = blockIdx.x * 256 + threadIdx.x; i < cnt; i += gridDim.x * 256) {
    u64 c = cands[i];
    const int m = (int)(c >> 32), n = (int)(u32)(c & 0xffffffffull);
    const float4* zr = (const float4*)(z + (size_t)m * 256);
    const float4* er = (const float4*)(cb + (size_t)n * 256);
    float acc = 0.f;
    for (int j = 0; j < 64; ++j) {   // strict k-ascending sequential fma (sgemm-faithful)
      float4 a = zr[j], b = er[j];
      acc = fmaf(a.x, b.x, acc); acc = fmaf(a.y, b.y, acc);
      acc = fmaf(a.z, b.z, acc); acc = fmaf(a.w, b.w, acc);
    }
    float d = fmaf(-2.f, acc, A[m]);  // = fl(A - 2*acc), single rounding
    u64 key = ((u64)__float_as_uint(d) << 32) | (u64)(u32)n;
    atomicMin(&keys[m], key);
  }
}

// ---------------- gather z_q, write z_q_st + indices, loss partials ----------------
__global__ __launch_bounds__(256) void vq_gather_new(
    const float* __restrict__ z, const float* __restrict__ cb,
    const u64* __restrict__ keys, float* __restrict__ idx_out,
    float* __restrict__ zq_out, double* __restrict__ loss_part) {
  __shared__ double lred[4];
  const int tid = threadIdx.x;
  const int rl = tid >> 2, part = tid & 3;
  const int R = blockIdx.x * 64 + rl;
  const int bi = (int)(u32)(keys[R] & 0xffffffffull);
  if (part == 0) idx_out[R] = (float)bi;
  const float4* zr = (const float4*)z + (size_t)R * 64 + part * 16;
  const float4* er = (const float4*)cb + (size_t)bi * 64 + part * 16;
  float4* orow = (float4*)zq_out + (size_t)R * 64 + part * 16;
  double lsum = 0.0;
#pragma unroll
  for (int i = 0; i < 16; ++i) {
    float4 zv = zr[i], ev = er[i];
    float dx = ev.x - zv.x, dy = ev.y - zv.y, dz = ev.z - zv.z, dw = ev.w - zv.w;
    float4 o; o.x = zv.x + dx; o.y = zv.y + dy; o.z = zv.z + dz; o.w = zv.w + dw;
    orow[i] = o;
    lsum += (double)dx * dx + (double)dy * dy + (double)dz * dz + (double)dw * dw;
  }
#pragma unroll
  for (int o = 32; o > 0; o >>= 1) lsum += __shfl_down(lsum, o, 64);
  if ((tid & 63) == 0) lred[tid >> 6] = lsum;
  __syncthreads();
  if (tid == 0) loss_part[blockIdx.x] = lred[0] + lred[1] + lred[2] + lred[3];
}

__global__ void vq_finalize_kernel(const double* __restrict__ loss_part,
                                   float* __restrict__ loss_out) {
  if (threadIdx.x == 0 && blockIdx.x == 0) {
    double s = 0.0;
    for (int b = 0; b < 512; ++b) s += loss_part[b];
    *loss_out = (float)(s / (double)ND_TOTAL * 1.25);
  }
}

// ================= fallback (proven round-2 path, used if ws too small) =================
__global__ __launch_bounds__(256) void vq_argmin_fb(
    const float* __restrict__ z, const float* __restrict__ cb,
    float* __restrict__ idx_out) {
  __shared__ float4 zs[64 * 64];
  const int tid = threadIdx.x;
  const int tc = tid & 15, tr = tid >> 4;
  const int rowbase = blockIdx.x * 64;
  const float4* zg4 = (const float4*)z;
  const float4* cb4 = (const float4*)cb;
  const int swz = (tr & 3) << 1;
#pragma unroll
  for (int i = 0; i < 16; ++i) {
    int idx = i * 256 + tid;
    int row = idx >> 6, dq = idx & 63;
    int col = dq ^ (((row >> 2) & 3) << 1);
    zs[row * 64 + col] = zg4[(size_t)rowbase * 64 + idx];
  }
  __syncthreads();
  float A[4];
#pragma unroll
  for (int r = 0; r < 4; ++r) {
    int row = tr * 4 + r;
    float p = 0.f;
#pragma unroll
    for (int j = 0; j < 4; ++j) {
      int dq = tc + 16 * j;
      float4 v = zs[row * 64 + (dq ^ swz)];
      p = fmaf(v.x, v.x, p); p = fmaf(v.y, v.y, p);
      p = fmaf(v.z, v.z, p); p = fmaf(v.w, v.w, p);
    }
#pragma unroll
    for (int m = 1; m <= 8; m <<= 1) p += __shfl_xor(p, m, 64);
    A[r] = p;
  }
  float b1[4] = {INFINITY, INFINITY, INFINITY, INFINITY};
  int   i1[4] = {0x7fffffff, 0x7fffffff, 0x7fffffff, 0x7fffffff};
  for (int kt = 0; kt < 64; ++kt) {
    const int e0 = kt * 128 + tc * 8;
    const float4* eb = cb4 + (size_t)e0 * 64;
    float acc[4][8];
#pragma unroll
    for (int r = 0; r < 4; ++r)
#pragma unroll
      for (int c = 0; c < 8; ++c) acc[r][c] = 0.f;
#pragma unroll 2
    for (int dq = 0; dq < 64; ++dq) {
      float4 ev[8];
#pragma unroll
      for (int c = 0; c < 8; ++c) ev[c] = eb[c * 64 + dq];
      const int col = dq ^ swz;
      float4 zv[4];
#pragma unroll
      for (int r = 0; r < 4; ++r) zv[r] = zs[(tr * 4 + r) * 64 + col];
#pragma unroll
      for (int r = 0; r < 4; ++r)
#pragma unroll
        for (int c = 0; c < 8; ++c) {
          acc[r][c] = fmaf(zv[r].x, ev[c].x, acc[r][c]);
          acc[r][c] = fmaf(zv[r].y, ev[c].y, acc[r][c]);
          acc[r][c] = fmaf(zv[r].z, ev[c].z, acc[r][c]);
          acc[r][c] = fmaf(zv[r].w, ev[c].w, acc[r][c]);
        }
    }
#pragma unroll
    for (int c = 0; c < 8; ++c)
#pragma unroll
      for (int r = 0; r < 4; ++r) {
        float d = A[r] - 2.0f * acc[r][c];
        if (d < b1[r]) { b1[r] = d; i1[r] = e0 + c; }
      }
  }
  __syncthreads();
  float* rs = (float*)zs;
  int*   ri = (int*)(rs + 64 * 16);
#pragma unroll
  for (int r = 0; r < 4; ++r) {
    rs[(tr * 4 + r) * 16 + tc] = b1[r];
    ri[(tr * 4 + r) * 16 + tc] = i1[r];
  }
  __syncthreads();
  if (tid < 64) {
    float B = INFINITY; int I = 0x7fffffff;
#pragma unroll
    for (int c = 0; c < 16; ++c) {
      float v = rs[tid * 16 + c];
      int  ix = ri[tid * 16 + c];
      if (v < B || (v == B && ix < I)) { B = v; I = ix; }
    }
    idx_out[rowbase + tid] = (float)I;
  }
}

__global__ __launch_bounds__(256) void vq_gather_fb(
    const float* __restrict__ z, const float* __restrict__ cb,
    const float* __restrict__ idx_out, float* __restrict__ zq_out,
    double* __restrict__ loss_part) {
  __shared__ double lred[4];
  const int tid = threadIdx.x;
  const int rl = tid >> 2, part = tid & 3;
  const int R = blockIdx.x * 64 + rl;
  const int bi = (int)idx_out[R];
  const float4* zr = (const float4*)z + (size_t)R * 64 + part * 16;
  const float4* er = (const float4*)cb + (size_t)bi * 64 + part * 16;
  float4* orow = (float4*)zq_out + (size_t)R * 64 + part * 16;
  double lsum = 0.0;
#pragma unroll
  for (int i = 0; i < 16; ++i) {
    float4 zv = zr[i], ev = er[i];
    float dx = ev.x - zv.x, dy = ev.y - zv.y, dz = ev.z - zv.z, dw = ev.w - zv.w;
    float4 o; o.x = zv.x + dx; o.y = zv.y + dy; o.z = zv.z + dz; o.w = zv.w + dw;
    orow[i] = o;
    lsum += (double)dx * dx + (double)dy * dy + (double)dz * dz + (double)dw * dw;
  }
#pragma unroll
  for (int o = 32; o > 0; o >>= 1) lsum += __shfl_down(lsum, o, 64);
  if ((tid & 63) == 0) lred[tid >> 6] = lsum;
  __syncthreads();
  if (tid == 0) loss_part[blockIdx.x] = lred[0] + lred[1] + lred[2] + lred[3];
}

extern "C" void kernel_launch(void* const* d_in, const int* in_sizes, int n_in,
                              void* d_out, int out_size, void* d_ws, size_t ws_size,
                              hipStream_t stream) {
  const float* z  = (const float*)d_in[0];
  const float* cb = (const float*)d_in[1];
  float* out = (float*)d_out;
  float* zq_out   = out;
  float* loss_out = out + ND_TOTAL;
  float* idx_out  = out + ND_TOTAL + 1;

  if (ws_size >= WS_NEEDED) {
    char* ws = (char*)d_ws;
    u32* counter          = (u32*)(ws + WS_COUNTER);
    float* A              = (float*)(ws + WS_A);
    float* marg           = (float*)(ws + WS_MARG);
    u64* keys             = (u64*)(ws + WS_KEYS);
    u64* cands            = (u64*)(ws + WS_CANDS);
    unsigned short* zh    = (unsigned short*)(ws + WS_ZH);
    unsigned short* eh    = (unsigned short*)(ws + WS_EH);
    double* loss_part     = (double*)(ws + WS_LOSS);

    vq_prep_z<<<NROWS / 4, 256, 0, stream>>>(z, zh, A, marg, keys);
    vq_prep_e<<<KENT / 4, 256, 0, stream>>>(cb, eh, counter);
    vq_fused<<<NROWS / 64, 256, 0, stream>>>(zh, eh, A, marg, cands, counter);
    vq_exact<<<2048, 256, 0, stream>>>(z, cb, A, cands, counter, keys);
    vq_gather_new<<<NROWS / 64, 256, 0, stream>>>(z, cb, keys, idx_out, zq_out, loss_part);
    vq_finalize_kernel<<<1, 64, 0, stream>>>(loss_part, loss_out);
  } else {
    double* loss_part = (double*)d_ws;   // [512]
    vq_argmin_fb<<<NROWS / 64, 256, 0, stream>>>(z, cb, idx_out);
    vq_gather_fb<<<NROWS / 64, 256, 0, stream>>>(z, cb, idx_out, zq_out, loss_part);
    vq_finalize_kernel<<<1, 64, 0, stream>>>(loss_part, loss_out);
  }
}

// Round 6
// 1840.725 us; speedup vs baseline: 3.8702x; 1.0417x over previous
//
#include <hip/hip_runtime.h>

typedef unsigned int u32;
typedef unsigned long long u64;
typedef unsigned short ushort_t;

#define NROWS 32768
#define KENT  8192
#define DDIM  256
#define ND_TOTAL 8388608
#define CAP   1048576u

// ---- workspace layout (bytes) ----
#define WS_COUNTER   0
#define WS_A         64
#define WS_MARG      131136
#define WS_KEYS      262208
#define WS_CANDS     524352
#define WS_ZH        8912960
#define WS_EH        25690176
#define WS_LOSS      29884480
#define WS_NEEDED    29888576ull

typedef __attribute__((ext_vector_type(8))) short s16x8;
typedef __attribute__((ext_vector_type(4))) float f32x4;

__device__ __forceinline__ unsigned short bf16_rne(float f) {
  u32 u = __float_as_uint(f);
  u32 r = (u + 0x7fffu + ((u >> 16) & 1u)) >> 16;
  return (unsigned short)r;
}

// async global->LDS: 16B/lane, LDS dest = wave-uniform base + lane*16
__device__ __forceinline__ void gll16(const void* g, void* l) {
  __builtin_amdgcn_global_load_lds((const __attribute__((address_space(1))) void*)g,
                                   (__attribute__((address_space(3))) void*)l, 16, 0, 0);
}

// ---------------- prep: z -> bf16, A, margin, init keys ----------------
__global__ __launch_bounds__(256) void vq_prep_z(
    const float* __restrict__ z, unsigned short* __restrict__ zh,
    float* __restrict__ A, float* __restrict__ marg, u64* __restrict__ keys) {
  const int wid = threadIdx.x >> 6, lane = threadIdx.x & 63;
  const int row = blockIdx.x * 4 + wid;
  float4 v = ((const float4*)z)[(size_t)row * 64 + lane];
  ushort4 h;
  h.x = bf16_rne(v.x); h.y = bf16_rne(v.y); h.z = bf16_rne(v.z); h.w = bf16_rne(v.w);
  *(ushort4*)&zh[(size_t)row * 256 + lane * 4] = h;
  double s  = (double)v.x * v.x + (double)v.y * v.y + (double)v.z * v.z + (double)v.w * v.w;
  double s1 = fabs((double)v.x) + fabs((double)v.y) + fabs((double)v.z) + fabs((double)v.w);
#pragma unroll
  for (int m = 1; m <= 32; m <<= 1) { s += __shfl_xor(s, m, 64); s1 += __shfl_xor(s1, m, 64); }
  if (lane == 0) {
    float Af = (float)s;
    u32 bits = __float_as_uint(Af);
    float ulpA = __uint_as_float((bits & 0x7f800000u) - (23u << 23));  // A >= 128 always
    A[row] = Af;
    // marg >= (ulpA + 2*E_dot) with big slack; proven rounds 3-5
    marg[row] = 4.0f * ulpA + 3.86e-6f * (float)s1 + 4e-6f;
    keys[row] = ~0ull;
  }
}

// ---------------- prep: codebook -> bf16, zero counter ----------------
__global__ __launch_bounds__(256) void vq_prep_e(
    const float* __restrict__ cb, unsigned short* __restrict__ eh,
    u32* __restrict__ counter) {
  if (blockIdx.x == 0 && threadIdx.x == 0) *counter = 0u;
  const int wid = threadIdx.x >> 6, lane = threadIdx.x & 63;
  const int row = blockIdx.x * 4 + wid;
  float4 v = ((const float4*)cb)[(size_t)row * 64 + lane];
  ushort4 h;
  h.x = bf16_rne(v.x); h.y = bf16_rne(v.y); h.z = bf16_rne(v.z); h.w = bf16_rne(v.w);
  *(ushort4*)&eh[(size_t)row * 256 + lane * 4] = h;
}

// ---------------- fused GEMM, pipelined (T3+T4): 128 rows/block, A in regs,
// B streamed via 8 LDS stage-buffers, counted vmcnt(6), raw s_barrier.
// Stage S: ct=(S>>3)&31, kt=S&7, buf=S&7. sweep0 = rowmin, sweep1 = emit. ----------------
__global__ __launch_bounds__(512, 2) void vq_fused2(
    const ushort_t* __restrict__ zh, const ushort_t* __restrict__ eh,
    const float* __restrict__ marg, u64* __restrict__ cands, u32* __restrict__ counter) {
  __shared__ __align__(16) ushort_t Bsm[8][8192];   // 8 bufs x 16KB = 128KB
  __shared__ float rowMinSm[128][4];

  const int tid = threadIdx.x, w = tid >> 6, lane = tid & 63;
  const int l15 = lane & 15, l4 = lane >> 4;
  const int wrow = (w >> 2) * 64, wcol = (w & 3) * 64;
  const int rowbase = blockIdx.x * 128;

  // ---- A fragments: registers for the whole kernel
  s16x8 areg[4][8];
#pragma unroll
  for (int fi = 0; fi < 4; ++fi)
#pragma unroll
    for (int kt = 0; kt < 8; ++kt)
      areg[fi][kt] = *(const s16x8*)(zh + (size_t)(rowbase + wrow + fi * 16 + l15) * 256
                                        + kt * 32 + l4 * 8);

  // ---- B staging: slot t in [0,1024) holds (entry e=t>>2, chunk (t&3)^((e>>1)&3))
  // thread stages slots t0 = w*128+lane and t0+64 (LDS dest linear, source pre-swizzled)
  const int t0 = w * 128 + lane, t1 = t0 + 64;
  const int e0s = t0 >> 2, e1s = t1 >> 2;
  const ushort_t* gsrc0 = eh + (size_t)e0s * 256 + (((t0 & 3) ^ ((e0s >> 1) & 3)) * 8);
  const ushort_t* gsrc1 = eh + (size_t)e1s * 256 + (((t1 & 3) ^ ((e1s >> 1) & 3)) * 8);
  const int wbase = w * 1024;   // ushort index of wave's 1KB staging base

#define ISSUE(BUF, CT, KT) do {                                          \
    size_t off_ = (size_t)(CT) * 65536 + (size_t)(KT) * 32;              \
    gll16(gsrc0 + off_, &Bsm[(BUF)][wbase]);                             \
    gll16(gsrc1 + off_, &Bsm[(BUF)][wbase + 512]);                       \
  } while (0)

  // swizzled read offsets (ushort index) for this thread's 4 B-fragments
  int boff[4];
#pragma unroll
  for (int fj = 0; fj < 4; ++fj) {
    int e = wcol + fj * 16 + l15;
    boff[fj] = e * 32 + (l4 ^ ((e >> 1) & 3)) * 8;
  }

  float runthr[4][4];
#pragma unroll
  for (int fi = 0; fi < 4; ++fi)
#pragma unroll
    for (int rg = 0; rg < 4; ++rg) runthr[fi][rg] = INFINITY;

  // prologue: 4 stages in flight
  ISSUE(0, 0, 0); ISSUE(1, 0, 1); ISSUE(2, 0, 2); ISSUE(3, 0, 3);

#pragma unroll 1
  for (int sweep = 0; sweep < 2; ++sweep) {
#pragma unroll 1
    for (int ct = 0; ct < 32; ++ct) {
      f32x4 acc[4][4];
#pragma unroll
      for (int fi = 0; fi < 4; ++fi)
#pragma unroll
        for (int fj = 0; fj < 4; ++fj) acc[fi][fj] = (f32x4){0.f, 0.f, 0.f, 0.f};

#pragma unroll
      for (int kt = 0; kt < 8; ++kt) {
        asm volatile("s_waitcnt vmcnt(6)" ::: "memory");   // oldest stage complete, 3 in flight
        __builtin_amdgcn_s_barrier();
        {
          const int ktn = (kt + 4) & 7;
          const int ctn = (kt >= 4) ? ((ct + 1) & 31) : ct;  // wraps across sweep; tail extra harmless
          ISSUE(ktn, ctn, ktn);
        }
        s16x8 bv[4];
#pragma unroll
        for (int fj = 0; fj < 4; ++fj)
          bv[fj] = *(const s16x8*)&Bsm[kt][boff[fj]];
#pragma unroll
        for (int fi = 0; fi < 4; ++fi)
#pragma unroll
          for (int fj = 0; fj < 4; ++fj)
            acc[fi][fj] = __builtin_amdgcn_mfma_f32_16x16x32_bf16(areg[fi][kt], bv[fj],
                                                                  acc[fi][fj], 0, 0, 0);
      }

      // per-ct epilogue (registers only); s = -2*acc is EXACT (no rounding),
      // identical instruction stream both sweeps -> bitwise-identical values
#pragma unroll
      for (int fi = 0; fi < 4; ++fi) {
#pragma unroll
        for (int rg = 0; rg < 4; ++rg) {
          float s0 = -2.0f * acc[fi][0][rg];
          float s1 = -2.0f * acc[fi][1][rg];
          float s2 = -2.0f * acc[fi][2][rg];
          float s3 = -2.0f * acc[fi][3][rg];
          if (sweep == 0) {
            runthr[fi][rg] = fminf(runthr[fi][rg], fminf(fminf(s0, s1), fminf(s2, s3)));
          } else {
            const float T = runthr[fi][rg];
            const int m = rowbase + wrow + fi * 16 + l4 * 4 + rg;
            const int nb = ct * 256 + wcol + l15;
            if (s0 <= T) { u32 p = atomicAdd(counter, 1u); if (p < CAP) cands[p] = ((u64)(u32)m << 32) | (u64)(u32)(nb); }
            if (s1 <= T) { u32 p = atomicAdd(counter, 1u); if (p < CAP) cands[p] = ((u64)(u32)m << 32) | (u64)(u32)(nb + 16); }
            if (s2 <= T) { u32 p = atomicAdd(counter, 1u); if (p < CAP) cands[p] = ((u64)(u32)m << 32) | (u64)(u32)(nb + 32); }
            if (s3 <= T) { u32 p = atomicAdd(counter, 1u); if (p < CAP) cands[p] = ((u64)(u32)m << 32) | (u64)(u32)(nb + 48); }
          }
        }
      }
    }

    if (sweep == 0) {
      // cross-lane (l15) + cross-wave (wcol quarters) rowmin, then threshold
#pragma unroll
      for (int fi = 0; fi < 4; ++fi)
#pragma unroll
        for (int rg = 0; rg < 4; ++rg) {
          float v = runthr[fi][rg];
#pragma unroll
          for (int msk = 1; msk <= 8; msk <<= 1) v = fminf(v, __shfl_xor(v, msk, 64));
          if (l15 == 0) rowMinSm[wrow + fi * 16 + l4 * 4 + rg][w & 3] = v;
        }
      __syncthreads();   // drains vmcnt(0): prefetched sweep-1 stages land in LDS, accounting resumes cleanly
#pragma unroll
      for (int fi = 0; fi < 4; ++fi)
#pragma unroll
        for (int rg = 0; rg < 4; ++rg) {
          const int rl = wrow + fi * 16 + l4 * 4 + rg;
          float mn = fminf(fminf(rowMinSm[rl][0], rowMinSm[rl][1]),
                           fminf(rowMinSm[rl][2], rowMinSm[rl][3]));
          runthr[fi][rg] = mn + marg[rowbase + rl];
        }
    }
  }
  asm volatile("s_waitcnt vmcnt(0)" ::: "memory");
#undef ISSUE
}

// ---------------- exact resolution: reference-bit-faithful f32 d ----------------
__global__ __launch_bounds__(256) void vq_exact(
    const float* __restrict__ z, const float* __restrict__ cb,
    const float* __restrict__ A, const u64* __restrict__ cands,
    const u32* __restrict__ counter, u64* __restrict__ keys) {
  u32 cnt = *counter; if (cnt > CAP) cnt = CAP;
  for (u32 i = blockIdx.x * 256 + threadIdx.x; i < cnt; i += gridDim.x * 256) {
    u64 c = cands[i];
    const int m = (int)(c >> 32), n = (int)(u32)(c & 0xffffffffull);
    const float4* zr = (const float4*)(z + (size_t)m * 256);
    const float4* er = (const float4*)(cb + (size_t)n * 256);
    float acc = 0.f;
    for (int j = 0; j < 64; ++j) {   // strict k-ascending sequential fma (sgemm-faithful)
      float4 a = zr[j], b = er[j];
      acc = fmaf(a.x, b.x, acc); acc = fmaf(a.y, b.y, acc);
      acc = fmaf(a.z, b.z, acc); acc = fmaf(a.w, b.w, acc);
    }
    float d = fmaf(-2.f, acc, A[m]);  // = fl(A - 2*acc), single rounding
    u64 key = ((u64)__float_as_uint(d) << 32) | (u64)(u32)n;
    atomicMin(&keys[m], key);
  }
}

// ---------------- gather z_q, write z_q_st + indices, loss partials ----------------
__global__ __launch_bounds__(256) void vq_gather_new(
    const float* __restrict__ z, const float* __restrict__ cb,
    const u64* __restrict__ keys, float* __restrict__ idx_out,
    float* __restrict__ zq_out, double* __restrict__ loss_part) {
  __shared__ double lred[4];
  const int tid = threadIdx.x;
  const int rl = tid >> 2, part = tid & 3;
  const int R = blockIdx.x * 64 + rl;
  const int bi = (int)(u32)(keys[R] & 0xffffffffull);
  if (part == 0) idx_out[R] = (float)bi;
  const float4* zr = (const float4*)z + (size_t)R * 64 + part * 16;
  const float4* er = (const float4*)cb + (size_t)bi * 64 + part * 16;
  float4* orow = (float4*)zq_out + (size_t)R * 64 + part * 16;
  double lsum = 0.0;
#pragma unroll
  for (int i = 0; i < 16; ++i) {
    float4 zv = zr[i], ev = er[i];
    float dx = ev.x - zv.x, dy = ev.y - zv.y, dz = ev.z - zv.z, dw = ev.w - zv.w;
    float4 o; o.x = zv.x + dx; o.y = zv.y + dy; o.z = zv.z + dz; o.w = zv.w + dw;
    orow[i] = o;
    lsum += (double)dx * dx + (double)dy * dy + (double)dz * dz + (double)dw * dw;
  }
#pragma unroll
  for (int o = 32; o > 0; o >>= 1) lsum += __shfl_down(lsum, o, 64);
  if ((tid & 63) == 0) lred[tid >> 6] = lsum;
  __syncthreads();
  if (tid == 0) loss_part[blockIdx.x] = lred[0] + lred[1] + lred[2] + lred[3];
}

__global__ void vq_finalize_kernel(const double* __restrict__ loss_part,
                                   float* __restrict__ loss_out) {
  if (threadIdx.x == 0 && blockIdx.x == 0) {
    double s = 0.0;
    for (int b = 0; b < 512; ++b) s += loss_part[b];
    *loss_out = (float)(s / (double)ND_TOTAL * 1.25);
  }
}

// ================= fallback (proven round-2 path, used if ws too small) =================
__global__ __launch_bounds__(256) void vq_argmin_fb(
    const float* __restrict__ z, const float* __restrict__ cb,
    float* __restrict__ idx_out) {
  __shared__ float4 zs[64 * 64];
  const int tid = threadIdx.x;
  const int tc = tid & 15, tr = tid >> 4;
  const int rowbase = blockIdx.x * 64;
  const float4* zg4 = (const float4*)z;
  const float4* cb4 = (const float4*)cb;
  const int swz = (tr & 3) << 1;
#pragma unroll
  for (int i = 0; i < 16; ++i) {
    int idx = i * 256 + tid;
    int row = idx >> 6, dq = idx & 63;
    int col = dq ^ (((row >> 2) & 3) << 1);
    zs[row * 64 + col] = zg4[(size_t)rowbase * 64 + idx];
  }
  __syncthreads();
  float A[4];
#pragma unroll
  for (int r = 0; r < 4; ++r) {
    int row = tr * 4 + r;
    float p = 0.f;
#pragma unroll
    for (int j = 0; j < 4; ++j) {
      int dq = tc + 16 * j;
      float4 v = zs[row * 64 + (dq ^ swz)];
      p = fmaf(v.x, v.x, p); p = fmaf(v.y, v.y, p);
      p = fmaf(v.z, v.z, p); p = fmaf(v.w, v.w, p);
    }
#pragma unroll
    for (int m = 1; m <= 8; m <<= 1) p += __shfl_xor(p, m, 64);
    A[r] = p;
  }
  float b1[4] = {INFINITY, INFINITY, INFINITY, INFINITY};
  int   i1[4] = {0x7fffffff, 0x7fffffff, 0x7fffffff, 0x7fffffff};
  for (int kt = 0; kt < 64; ++kt) {
    const int e0 = kt * 128 + tc * 8;
    const float4* eb = cb4 + (size_t)e0 * 64;
    float acc[4][8];
#pragma unroll
    for (int r = 0; r < 4; ++r)
#pragma unroll
      for (int c = 0; c < 8; ++c) acc[r][c] = 0.f;
#pragma unroll 2
    for (int dq = 0; dq < 64; ++dq) {
      float4 ev[8];
#pragma unroll
      for (int c = 0; c < 8; ++c) ev[c] = eb[c * 64 + dq];
      const int col = dq ^ swz;
      float4 zv[4];
#pragma unroll
      for (int r = 0; r < 4; ++r) zv[r] = zs[(tr * 4 + r) * 64 + col];
#pragma unroll
      for (int r = 0; r < 4; ++r)
#pragma unroll
        for (int c = 0; c < 8; ++c) {
          acc[r][c] = fmaf(zv[r].x, ev[c].x, acc[r][c]);
          acc[r][c] = fmaf(zv[r].y, ev[c].y, acc[r][c]);
          acc[r][c] = fmaf(zv[r].z, ev[c].z, acc[r][c]);
          acc[r][c] = fmaf(zv[r].w, ev[c].w, acc[r][c]);
        }
    }
#pragma unroll
    for (int c = 0; c < 8; ++c)
#pragma unroll
      for (int r = 0; r < 4; ++r) {
        float d = A[r] - 2.0f * acc[r][c];
        if (d < b1[r]) { b1[r] = d; i1[r] = e0 + c; }
      }
  }
  __syncthreads();
  float* rs = (float*)zs;
  int*   ri = (int*)(rs + 64 * 16);
#pragma unroll
  for (int r = 0; r < 4; ++r) {
    rs[(tr * 4 + r) * 16 + tc] = b1[r];
    ri[(tr * 4 + r) * 16 + tc] = i1[r];
  }
  __syncthreads();
  if (tid < 64) {
    float B = INFINITY; int I = 0x7fffffff;
#pragma unroll
    for (int c = 0; c < 16; ++c) {
      float v = rs[tid * 16 + c];
      int  ix = ri[tid * 16 + c];
      if (v < B || (v == B && ix < I)) { B = v; I = ix; }
    }
    idx_out[rowbase + tid] = (float)I;
  }
}

__global__ __launch_bounds__(256) void vq_gather_fb(
    const float* __restrict__ z, const float* __restrict__ cb,
    const float* __restrict__ idx_out, float* __restrict__ zq_out,
    double* __restrict__ loss_part) {
  __shared__ double lred[4];
  const int tid = threadIdx.x;
  const int rl = tid >> 2, part = tid & 3;
  const int R = blockIdx.x * 64 + rl;
  const int bi = (int)idx_out[R];
  const float4* zr = (const float4*)z + (size_t)R * 64 + part * 16;
  const float4* er = (const float4*)cb + (size_t)bi * 64 + part * 16;
  float4* orow = (float4*)zq_out + (size_t)R * 64 + part * 16;
  double lsum = 0.0;
#pragma unroll
  for (int i = 0; i < 16; ++i) {
    float4 zv = zr[i], ev = er[i];
    float dx = ev.x - zv.x, dy = ev.y - zv.y, dz = ev.z - zv.z, dw = ev.w - zv.w;
    float4 o; o.x = zv.x + dx; o.y = zv.y + dy; o.z = zv.z + dz; o.w = zv.w + dw;
    orow[i] = o;
    lsum += (double)dx * dx + (double)dy * dy + (double)dz * dz + (double)dw * dw;
  }
#pragma unroll
  for (int o = 32; o > 0; o >>= 1) lsum += __shfl_down(lsum, o, 64);
  if ((tid & 63) == 0) lred[tid >> 6] = lsum;
  __syncthreads();
  if (tid == 0) loss_part[blockIdx.x] = lred[0] + lred[1] + lred[2] + lred[3];
}

extern "C" void kernel_launch(void* const* d_in, const int* in_sizes, int n_in,
                              void* d_out, int out_size, void* d_ws, size_t ws_size,
                              hipStream_t stream) {
  const float* z  = (const float*)d_in[0];
  const float* cb = (const float*)d_in[1];
  float* out = (float*)d_out;
  float* zq_out   = out;
  float* loss_out = out + ND_TOTAL;
  float* idx_out  = out + ND_TOTAL + 1;

  if (ws_size >= WS_NEEDED) {
    char* ws = (char*)d_ws;
    u32* counter          = (u32*)(ws + WS_COUNTER);
    float* A              = (float*)(ws + WS_A);
    float* marg           = (float*)(ws + WS_MARG);
    u64* keys             = (u64*)(ws + WS_KEYS);
    u64* cands            = (u64*)(ws + WS_CANDS);
    unsigned short* zh    = (unsigned short*)(ws + WS_ZH);
    unsigned short* eh    = (unsigned short*)(ws + WS_EH);
    double* loss_part     = (double*)(ws + WS_LOSS);

    vq_prep_z<<<NROWS / 4, 256, 0, stream>>>(z, zh, A, marg, keys);
    vq_prep_e<<<KENT / 4, 256, 0, stream>>>(cb, eh, counter);
    vq_fused2<<<NROWS / 128, 512, 0, stream>>>(zh, eh, marg, cands, counter);
    vq_exact<<<1024, 256, 0, stream>>>(z, cb, A, cands, counter, keys);
    vq_gather_new<<<NROWS / 64, 256, 0, stream>>>(z, cb, keys, idx_out, zq_out, loss_part);
    vq_finalize_kernel<<<1, 64, 0, stream>>>(loss_part, loss_out);
  } else {
    double* loss_part = (double*)d_ws;   // [512]
    vq_argmin_fb<<<NROWS / 64, 256, 0, stream>>>(z, cb, idx_out);
    vq_gather_fb<<<NROWS / 64, 256, 0, stream>>>(z, cb, idx_out, zq_out, loss_part);
    vq_finalize_kernel<<<1, 64, 0, stream>>>(loss_part, loss_out);
  }
}

// Round 8
// 342.420 us; speedup vs baseline: 20.8047x; 5.3756x over previous
//
#include <hip/hip_runtime.h>

typedef unsigned int u32;
typedef unsigned long long u64;
typedef unsigned short ushort_t;

#define NROWS 32768
#define KENT  8192
#define DDIM  256
#define ND_TOTAL 8388608
#define CAP   1048576u
#define LBUF  3072

// ---- workspace layout (bytes) ----
#define WS_COUNTER   0
#define WS_A         64
#define WS_MARG      131136
#define WS_ROWTHR    262208
#define WS_KEYS      393280
#define WS_CANDS     655424
#define WS_ZH        9044032
#define WS_EH        25821248
#define WS_LOSS      30015552
#define WS_NEEDED    30019648ull

typedef __attribute__((ext_vector_type(8))) short s16x8;
typedef __attribute__((ext_vector_type(4))) float f32x4;

__device__ __forceinline__ unsigned short bf16_rne(float f) {
  u32 u = __float_as_uint(f);
  u32 r = (u + 0x7fffu + ((u >> 16) & 1u)) >> 16;
  return (unsigned short)r;
}

// monotone float<->u32 key; smaller float => smaller key
__device__ __forceinline__ u32 fkey(float s) {
  u32 b = __float_as_uint(s);
  u32 mask = (u32)((int)b >> 31);
  return b ^ (mask | 0x80000000u);
}
__device__ __forceinline__ float unkey(u32 k) {
  u32 b = (k & 0x80000000u) ? (k ^ 0x80000000u) : ~k;
  return __uint_as_float(b);
}
#define KEY_INF 0xFF800000u   // fkey(+inf); unkey(KEY_INF) = +inf (NOT 0xFFFFFFFF: that's NaN)

// async global->LDS: 16B/lane, LDS dest = wave-uniform base + lane*16
__device__ __forceinline__ void gll16(const void* g, void* l) {
  __builtin_amdgcn_global_load_lds((const __attribute__((address_space(1))) void*)g,
                                   (__attribute__((address_space(3))) void*)l, 16, 0, 0);
}

// ---------------- prep: z -> bf16, A, margin, init keys ----------------
__global__ __launch_bounds__(256) void vq_prep_z(
    const float* __restrict__ z, unsigned short* __restrict__ zh,
    float* __restrict__ A, float* __restrict__ marg, u64* __restrict__ keys) {
  const int wid = threadIdx.x >> 6, lane = threadIdx.x & 63;
  const int row = blockIdx.x * 4 + wid;
  float4 v = ((const float4*)z)[(size_t)row * 64 + lane];
  ushort4 h;
  h.x = bf16_rne(v.x); h.y = bf16_rne(v.y); h.z = bf16_rne(v.z); h.w = bf16_rne(v.w);
  *(ushort4*)&zh[(size_t)row * 256 + lane * 4] = h;
  double s  = (double)v.x * v.x + (double)v.y * v.y + (double)v.z * v.z + (double)v.w * v.w;
  double s1 = fabs((double)v.x) + fabs((double)v.y) + fabs((double)v.z) + fabs((double)v.w);
#pragma unroll
  for (int m = 1; m <= 32; m <<= 1) { s += __shfl_xor(s, m, 64); s1 += __shfl_xor(s1, m, 64); }
  if (lane == 0) {
    float Af = (float)s;
    u32 bits = __float_as_uint(Af);
    float ulpA = __uint_as_float((bits & 0x7f800000u) - (23u << 23));  // A >= 128 always
    A[row] = Af;
    // marg >= 2*ulpA + 2*E_dot (bf16-conversion bound); proven rounds 3-6
    marg[row] = 4.0f * ulpA + 3.86e-6f * (float)s1 + 4e-6f;
    keys[row] = ~0ull;
  }
}

// ---------------- prep: codebook -> bf16, zero counter ----------------
__global__ __launch_bounds__(256) void vq_prep_e(
    const float* __restrict__ cb, unsigned short* __restrict__ eh,
    u32* __restrict__ counter) {
  if (blockIdx.x == 0 && threadIdx.x == 0) *counter = 0u;
  const int wid = threadIdx.x >> 6, lane = threadIdx.x & 63;
  const int row = blockIdx.x * 4 + wid;
  float4 v = ((const float4*)cb)[(size_t)row * 64 + lane];
  ushort4 h;
  h.x = bf16_rne(v.x); h.y = bf16_rne(v.y); h.z = bf16_rne(v.z); h.w = bf16_rne(v.w);
  *(ushort4*)&eh[(size_t)row * 256 + lane * 4] = h;
}

// ---------------- fused single-sweep GEMM + in-block exact resolution ----------------
// 512 blocks x 64 rows (block-private), 4 waves (32r x 128c each), A in regs,
// B dbuf 2x16KB via global_load_lds (XOR-swizzled both sides), 2-phase barrier
// pipeline. Tile sequence [0,1..31,0]: tile 0 warmup (min only, no emission),
// reprocessed at the end under the tightened threshold. Candidates go to an
// LDS buffer (block owns all cols of its rows); resolved in-block with the
// bit-faithful sequential-fmaf f32 distance; global cands/counter = overflow
// backstop only.
__global__ __launch_bounds__(256, 2) void vq_fused4(
    const ushort_t* __restrict__ zh, const ushort_t* __restrict__ eh,
    const float* __restrict__ z, const float* __restrict__ cb,
    const float* __restrict__ Ag, const float* __restrict__ marg,
    float* __restrict__ rowthr, u64* __restrict__ keys,
    u64* __restrict__ cands, u32* __restrict__ counter) {
  __shared__ __align__(16) ushort_t Bsm[2][8192];   // 2 x 16KB (256 entries x 32 dims)
  __shared__ u32 rowKey[64];
  __shared__ u64 lbuf[LBUF];                        // 24KB
  __shared__ u32 lcount;
  __shared__ u32 gbase;
  __shared__ float thrF[64];

  const int tid = threadIdx.x, w = tid >> 6, lane = tid & 63;
  const int l15 = lane & 15, l4 = lane >> 4;
  const int wrow = (w >> 1) * 32, wcol = (w & 1) * 128;
  const int rowbase = blockIdx.x * 64;

  if (tid < 64) rowKey[tid] = KEY_INF;
  if (tid == 0) lcount = 0u;

  // ---- A fragments in registers (64 VGPR)
  s16x8 areg[2][8];
#pragma unroll
  for (int fi = 0; fi < 2; ++fi)
#pragma unroll
    for (int kt = 0; kt < 8; ++kt)
      areg[fi][kt] = *(const s16x8*)(zh + (size_t)(rowbase + wrow + fi * 16 + l15) * 256
                                        + kt * 32 + l4 * 8);
  // per-thread row margins
  float mg[2][4];
#pragma unroll
  for (int fi = 0; fi < 2; ++fi)
#pragma unroll
    for (int rg = 0; rg < 4; ++rg)
      mg[fi][rg] = marg[rowbase + wrow + fi * 16 + l4 * 4 + rg];

  // ---- B staging: slot t in [0,1024): entry e=t>>2, stored chunk c=t&3 holds
  // global chunk c ^ ((e>>1)&3). Linear LDS dest; pre-swizzled global source.
  const int tb = w * 256 + lane;
  const ushort_t *gs0, *gs1, *gs2, *gs3;
  {
    int t, e;
    t = tb;        e = t >> 2; gs0 = eh + (size_t)e * 256 + (((t & 3) ^ ((e >> 1) & 3)) * 8);
    t = tb + 64;   e = t >> 2; gs1 = eh + (size_t)e * 256 + (((t & 3) ^ ((e >> 1) & 3)) * 8);
    t = tb + 128;  e = t >> 2; gs2 = eh + (size_t)e * 256 + (((t & 3) ^ ((e >> 1) & 3)) * 8);
    t = tb + 192;  e = t >> 2; gs3 = eh + (size_t)e * 256 + (((t & 3) ^ ((e >> 1) & 3)) * 8);
  }

#define ISSUE(BUF, CT, KT) do {                                        \
    size_t o_ = (size_t)(CT) * 65536 + (size_t)(KT) * 32;              \
    gll16(gs0 + o_, &Bsm[(BUF)][w * 2048]);                            \
    gll16(gs1 + o_, &Bsm[(BUF)][w * 2048 + 512]);                      \
    gll16(gs2 + o_, &Bsm[(BUF)][w * 2048 + 1024]);                     \
    gll16(gs3 + o_, &Bsm[(BUF)][w * 2048 + 1536]);                     \
  } while (0)

  // swizzled read offsets (ushort index) for this thread's 8 B-fragments
  int boff[8];
#pragma unroll
  for (int fj = 0; fj < 8; ++fj) {
    int e = wcol + fj * 16 + l15;
    boff[fj] = e * 32 + (l4 ^ ((e >> 1) & 3)) * 8;
  }

  ISSUE(0, 0, 0);
  __syncthreads();                       // covers LDS init + first stage
  int cur = 0;

#pragma unroll 1
  for (int it = 0; it <= 32; ++it) {
    const int ct = (it < 32) ? it : 0;   // tile 0 twice: warmup + final emission
    f32x4 acc[2][8];
#pragma unroll
    for (int fi = 0; fi < 2; ++fi)
#pragma unroll
      for (int fj = 0; fj < 8; ++fj) acc[fi][fj] = (f32x4){0.f, 0.f, 0.f, 0.f};

#pragma unroll
    for (int kt = 0; kt < 8; ++kt) {
      if (kt < 7)       ISSUE(cur ^ 1, ct, kt + 1);
      else if (it < 32) ISSUE(cur ^ 1, (it + 1 < 32) ? (it + 1) : 0, 0);
#pragma unroll
      for (int fj = 0; fj < 8; ++fj) {
        s16x8 bv = *(const s16x8*)&Bsm[cur][boff[fj]];
        acc[0][fj] = __builtin_amdgcn_mfma_f32_16x16x32_bf16(areg[0][kt], bv, acc[0][fj], 0, 0, 0);
        acc[1][fj] = __builtin_amdgcn_mfma_f32_16x16x32_bf16(areg[1][kt], bv, acc[1][fj], 0, 0, 0);
      }
      __syncthreads();                   // drains vmcnt: buf cur^1 ready
      cur ^= 1;
    }

    // per-tile epilogue: s = -2*acc (exact, identical DAG when recomputed)
#pragma unroll
    for (int fi = 0; fi < 2; ++fi) {
#pragma unroll
      for (int rg = 0; rg < 4; ++rg) {
        const int rl = wrow + fi * 16 + l4 * 4 + rg;
        float sv[8];
#pragma unroll
        for (int fj = 0; fj < 8; ++fj) sv[fj] = -2.0f * acc[fi][fj][rg];
        float smin = sv[0];
#pragma unroll
        for (int fj = 1; fj < 8; ++fj) smin = fminf(smin, sv[fj]);
        u32 kc = rowKey[rl];                     // stale read => conservative thr
        u32 nk = fkey(smin);
        if (nk < kc) atomicMin(&rowKey[rl], nk);
        if (it >= 1) {
          const float thr = unkey(kc) + mg[fi][rg];
          const int nb = ct * 256 + wcol + l15;
#pragma unroll
          for (int fj = 0; fj < 8; ++fj) {
            if (sv[fj] <= thr) {
              u64 pk = ((u64)__float_as_uint(sv[fj]) << 32) | ((u64)(u32)rl << 13)
                     | (u64)(u32)(nb + fj * 16);
              u32 lp = atomicAdd(&lcount, 1u);
              if (lp < LBUF) lbuf[lp] = pk;
              else {                             // overflow backstop -> global list
                u32 p = atomicAdd(counter, 1u);
                if (p < CAP) cands[p] = pk + ((u64)(u32)rowbase << 13);
              }
            }
          }
        }
      }
    }
  }

  // ---- in-block exact resolution ----
  __syncthreads();
  if (tid < 64) {
    float t = unkey(rowKey[tid]) + marg[rowbase + tid];
    thrF[tid] = t;
    rowthr[rowbase + tid] = t;                   // for the overflow backstop kernel
  }
  __syncthreads();
  u32 tl = lcount; if (tl > LBUF) tl = LBUF;
  for (u32 i = tid; i < tl; i += 256) {
    u64 c = lbuf[i];
    float s = __uint_as_float((u32)(c >> 32));
    const int rl = (int)((c >> 13) & 63u);
    const int n  = (int)(c & 0x1fffu);
    if (s > thrF[rl]) continue;                  // final-margin filter
    const int m = rowbase + rl;
    const float4* zr = (const float4*)(z + (size_t)m * 256);
    const float4* er = (const float4*)(cb + (size_t)n * 256);
    float acc = 0.f;
    for (int j = 0; j < 64; ++j) {   // strict k-ascending sequential fma (sgemm-faithful)
      float4 a = zr[j], b = er[j];
      acc = fmaf(a.x, b.x, acc); acc = fmaf(a.y, b.y, acc);
      acc = fmaf(a.z, b.z, acc); acc = fmaf(a.w, b.w, acc);
    }
    float d = fmaf(-2.f, acc, Ag[m]);  // = fl(A - 2*acc), single rounding
    u64 key = ((u64)__float_as_uint(d) << 32) | (u64)(u32)n;
    atomicMin(&keys[m], key);
  }
  (void)gbase;
#undef ISSUE
}

// ---------------- overflow backstop: exact eval of spilled candidates ----------------
__global__ __launch_bounds__(256) void vq_exact2(
    const float* __restrict__ z, const float* __restrict__ cb,
    const float* __restrict__ A, const float* __restrict__ rowthr,
    const u64* __restrict__ cands, const u32* __restrict__ counter,
    u64* __restrict__ keys) {
  u32 cnt = *counter; if (cnt > CAP) cnt = CAP;
  for (u32 i = blockIdx.x * 256 + threadIdx.x; i < cnt; i += gridDim.x * 256) {
    u64 c = cands[i];
    float s = __uint_as_float((u32)(c >> 32));
    const int m = (int)((c >> 13) & 0x7fffu);
    const int n = (int)(c & 0x1fffu);
    if (s > rowthr[m]) continue;
    const float4* zr = (const float4*)(z + (size_t)m * 256);
    const float4* er = (const float4*)(cb + (size_t)n * 256);
    float acc = 0.f;
    for (int j = 0; j < 64; ++j) {
      float4 a = zr[j], b = er[j];
      acc = fmaf(a.x, b.x, acc); acc = fmaf(a.y, b.y, acc);
      acc = fmaf(a.z, b.z, acc); acc = fmaf(a.w, b.w, acc);
    }
    float d = fmaf(-2.f, acc, A[m]);
    u64 key = ((u64)__float_as_uint(d) << 32) | (u64)(u32)n;
    atomicMin(&keys[m], key);
  }
}

// ---------------- gather z_q, write z_q_st + indices, loss partials ----------------
__global__ __launch_bounds__(256) void vq_gather_new(
    const float* __restrict__ z, const float* __restrict__ cb,
    const u64* __restrict__ keys, float* __restrict__ idx_out,
    float* __restrict__ zq_out, double* __restrict__ loss_part) {
  __shared__ double lred[4];
  const int tid = threadIdx.x;
  const int rl = tid >> 2, part = tid & 3;
  const int R = blockIdx.x * 64 + rl;
  const int bi = (int)(keys[R] & 0x1fffull);     // clamped: fault insurance
  if (part == 0) idx_out[R] = (float)bi;
  const float4* zr = (const float4*)z + (size_t)R * 64 + part * 16;
  const float4* er = (const float4*)cb + (size_t)bi * 64 + part * 16;
  float4* orow = (float4*)zq_out + (size_t)R * 64 + part * 16;
  double lsum = 0.0;
#pragma unroll
  for (int i = 0; i < 16; ++i) {
    float4 zv = zr[i], ev = er[i];
    float dx = ev.x - zv.x, dy = ev.y - zv.y, dz = ev.z - zv.z, dw = ev.w - zv.w;
    float4 o; o.x = zv.x + dx; o.y = zv.y + dy; o.z = zv.z + dz; o.w = zv.w + dw;
    orow[i] = o;
    lsum += (double)dx * dx + (double)dy * dy + (double)dz * dz + (double)dw * dw;
  }
#pragma unroll
  for (int o = 32; o > 0; o >>= 1) lsum += __shfl_down(lsum, o, 64);
  if ((tid & 63) == 0) lred[tid >> 6] = lsum;
  __syncthreads();
  if (tid == 0) loss_part[blockIdx.x] = lred[0] + lred[1] + lred[2] + lred[3];
}

__global__ void vq_finalize_kernel(const double* __restrict__ loss_part,
                                   float* __restrict__ loss_out) {
  if (threadIdx.x == 0 && blockIdx.x == 0) {
    double s = 0.0;
    for (int b = 0; b < 512; ++b) s += loss_part[b];
    *loss_out = (float)(s / (double)ND_TOTAL * 1.25);
  }
}

// ================= fallback (proven round-2 path, used if ws too small) =================
__global__ __launch_bounds__(256) void vq_argmin_fb(
    const float* __restrict__ z, const float* __restrict__ cb,
    float* __restrict__ idx_out) {
  __shared__ float4 zs[64 * 64];
  const int tid = threadIdx.x;
  const int tc = tid & 15, tr = tid >> 4;
  const int rowbase = blockIdx.x * 64;
  const float4* zg4 = (const float4*)z;
  const float4* cb4 = (const float4*)cb;
  const int swz = (tr & 3) << 1;
#pragma unroll
  for (int i = 0; i < 16; ++i) {
    int idx = i * 256 + tid;
    int row = idx >> 6, dq = idx & 63;
    int col = dq ^ (((row >> 2) & 3) << 1);
    zs[row * 64 + col] = zg4[(size_t)rowbase * 64 + idx];
  }
  __syncthreads();
  float A[4];
#pragma unroll
  for (int r = 0; r < 4; ++r) {
    int row = tr * 4 + r;
    float p = 0.f;
#pragma unroll
    for (int j = 0; j < 4; ++j) {
      int dq = tc + 16 * j;
      float4 v = zs[row * 64 + (dq ^ swz)];
      p = fmaf(v.x, v.x, p); p = fmaf(v.y, v.y, p);
      p = fmaf(v.z, v.z, p); p = fmaf(v.w, v.w, p);
    }
#pragma unroll
    for (int m = 1; m <= 8; m <<= 1) p += __shfl_xor(p, m, 64);
    A[r] = p;
  }
  float b1[4] = {INFINITY, INFINITY, INFINITY, INFINITY};
  int   i1[4] = {0x7fffffff, 0x7fffffff, 0x7fffffff, 0x7fffffff};
  for (int kt = 0; kt < 64; ++kt) {
    const int e0 = kt * 128 + tc * 8;
    const float4* eb = cb4 + (size_t)e0 * 64;
    float acc[4][8];
#pragma unroll
    for (int r = 0; r < 4; ++r)
#pragma unroll
      for (int c = 0; c < 8; ++c) acc[r][c] = 0.f;
#pragma unroll 2
    for (int dq = 0; dq < 64; ++dq) {
      float4 ev[8];
#pragma unroll
      for (int c = 0; c < 8; ++c) ev[c] = eb[c * 64 + dq];
      const int col = dq ^ swz;
      float4 zv[4];
#pragma unroll
      for (int r = 0; r < 4; ++r) zv[r] = zs[(tr * 4 + r) * 64 + col];
#pragma unroll
      for (int r = 0; r < 4; ++r)
#pragma unroll
        for (int c = 0; c < 8; ++c) {
          acc[r][c] = fmaf(zv[r].x, ev[c].x, acc[r][c]);
          acc[r][c] = fmaf(zv[r].y, ev[c].y, acc[r][c]);
          acc[r][c] = fmaf(zv[r].z, ev[c].z, acc[r][c]);
          acc[r][c] = fmaf(zv[r].w, ev[c].w, acc[r][c]);
        }
    }
#pragma unroll
    for (int c = 0; c < 8; ++c)
#pragma unroll
      for (int r = 0; r < 4; ++r) {
        float d = A[r] - 2.0f * acc[r][c];
        if (d < b1[r]) { b1[r] = d; i1[r] = e0 + c; }
      }
  }
  __syncthreads();
  float* rs = (float*)zs;
  int*   ri = (int*)(rs + 64 * 16);
#pragma unroll
  for (int r = 0; r < 4; ++r) {
    rs[(tr * 4 + r) * 16 + tc] = b1[r];
    ri[(tr * 4 + r) * 16 + tc] = i1[r];
  }
  __syncthreads();
  if (tid < 64) {
    float B = INFINITY; int I = 0x7fffffff;
#pragma unroll
    for (int c = 0; c < 16; ++c) {
      float v = rs[tid * 16 + c];
      int  ix = ri[tid * 16 + c];
      if (v < B || (v == B && ix < I)) { B = v; I = ix; }
    }
    idx_out[rowbase + tid] = (float)I;
  }
}

__global__ __launch_bounds__(256) void vq_gather_fb(
    const float* __restrict__ z, const float* __restrict__ cb,
    const float* __restrict__ idx_out, float* __restrict__ zq_out,
    double* __restrict__ loss_part) {
  __shared__ double lred[4];
  const int tid = threadIdx.x;
  const int rl = tid >> 2, part = tid & 3;
  const int R = blockIdx.x * 64 + rl;
  const int bi = (int)idx_out[R];
  const float4* zr = (const float4*)z + (size_t)R * 64 + part * 16;
  const float4* er = (const float4*)cb + (size_t)bi * 64 + part * 16;
  float4* orow = (float4*)zq_out + (size_t)R * 64 + part * 16;
  double lsum = 0.0;
#pragma unroll
  for (int i = 0; i < 16; ++i) {
    float4 zv = zr[i], ev = er[i];
    float dx = ev.x - zv.x, dy = ev.y - zv.y, dz = ev.z - zv.z, dw = ev.w - zv.w;
    float4 o; o.x = zv.x + dx; o.y = zv.y + dy; o.z = zv.z + dz; o.w = zv.w + dw;
    orow[i] = o;
    lsum += (double)dx * dx + (double)dy * dy + (double)dz * dz + (double)dw * dw;
  }
#pragma unroll
  for (int o = 32; o > 0; o >>= 1) lsum += __shfl_down(lsum, o, 64);
  if ((tid & 63) == 0) lred[tid >> 6] = lsum;
  __syncthreads();
  if (tid == 0) loss_part[blockIdx.x] = lred[0] + lred[1] + lred[2] + lred[3];
}

extern "C" void kernel_launch(void* const* d_in, const int* in_sizes, int n_in,
                              void* d_out, int out_size, void* d_ws, size_t ws_size,
                              hipStream_t stream) {
  const float* z  = (const float*)d_in[0];
  const float* cb = (const float*)d_in[1];
  float* out = (float*)d_out;
  float* zq_out   = out;
  float* loss_out = out + ND_TOTAL;
  float* idx_out  = out + ND_TOTAL + 1;

  if (ws_size >= WS_NEEDED) {
    char* ws = (char*)d_ws;
    u32* counter          = (u32*)(ws + WS_COUNTER);
    float* A              = (float*)(ws + WS_A);
    float* marg           = (float*)(ws + WS_MARG);
    float* rowthr         = (float*)(ws + WS_ROWTHR);
    u64* keys             = (u64*)(ws + WS_KEYS);
    u64* cands            = (u64*)(ws + WS_CANDS);
    unsigned short* zh    = (unsigned short*)(ws + WS_ZH);
    unsigned short* eh    = (unsigned short*)(ws + WS_EH);
    double* loss_part     = (double*)(ws + WS_LOSS);

    vq_prep_z<<<NROWS / 4, 256, 0, stream>>>(z, zh, A, marg, keys);
    vq_prep_e<<<KENT / 4, 256, 0, stream>>>(cb, eh, counter);
    vq_fused4<<<NROWS / 64, 256, 0, stream>>>(zh, eh, z, cb, A, marg, rowthr, keys, cands, counter);
    vq_exact2<<<256, 256, 0, stream>>>(z, cb, A, rowthr, cands, counter, keys);
    vq_gather_new<<<NROWS / 64, 256, 0, stream>>>(z, cb, keys, idx_out, zq_out, loss_part);
    vq_finalize_kernel<<<1, 64, 0, stream>>>(loss_part, loss_out);
  } else {
    double* loss_part = (double*)d_ws;   // [512]
    vq_argmin_fb<<<NROWS / 64, 256, 0, stream>>>(z, cb, idx_out);
    vq_gather_fb<<<NROWS / 64, 256, 0, stream>>>(z, cb, idx_out, zq_out, loss_part);
    vq_finalize_kernel<<<1, 64, 0, stream>>>(loss_part, loss_out);
  }
}